// Round 1
// baseline (2830.628 us; speedup 1.0000x reference)
//
#include <hip/hip_runtime.h>
#include <cstdint>
#include <cstddef>

#define B_   32
#define L_   12
#define N_   883
#define DM_  64
#define E_SP 14128
#define E_TP 144
#define NT_  12
#define RBN  28256      // B*N
#define RBL  384        // B*L
#define LDM  768        // L*DM
#define NDM  56512      // N*DM

static inline int cdiv_h(int a, int b){ return (a+b-1)/b; }

// ============================ res: X = hist @ start_w + start_b ============================
// res layout: [(b*N+n), l*64+d]  (row-major 768 cols)
__global__ void k_res(const float* __restrict__ hist, const float* __restrict__ sw,
                      const float* __restrict__ sb, float* __restrict__ res)
{
    int idx = blockIdx.x*256 + threadIdx.x;
    if (idx >= RBN*LDM) return;
    int r = idx / LDM, col = idx - r*LDM;
    int b = r / N_, n = r - b*N_;
    int l = col >> 6, d = col & 63;
    const float* hp = hist + ((size_t)(b*L_ + l)*N_ + n)*3;
    res[idx] = hp[0]*sw[d] + hp[1]*sw[64+d] + hp[2]*sw[128+d] + sb[d];
}

// ============================ generic fp32 GEMM: C = act(A@W + bias [+C]) =================
// AMODE 0: A[r*K+k].  AMODE 1: r=(b*883+n), k=(l*64+d), A addr = ((b*12+l)*883+n)*64+d.
// CMODE 0: C[r*N+c].  CMODE 1: r=(b*883+n), C addr = (b*12+c)*883+n  (final output scatter).
template<int AMODE, int CMODE, bool RELU, bool ADDTO>
__launch_bounds__(256)
__global__ void gemm_k(const float* __restrict__ A, const float* __restrict__ W,
                       const float* __restrict__ bias, float* __restrict__ C,
                       int M, int N, int K)
{
    __shared__ float As[16][64];
    __shared__ float Ws[16][64];
    const int t  = threadIdx.x;
    const int ty = t >> 4, tx = t & 15;
    const int row0 = blockIdx.y << 6, col0 = blockIdx.x << 6;
    const int lm = t >> 2, lk = (t & 3) << 2;   // A staging: 4 consecutive k for row lm
    const int wk = t >> 4, wj = (t & 15) << 2;  // W staging: 4 consecutive j for k=wk
    float acc[4][4] = {};
    const int ar = row0 + lm;
    const bool avalid = ar < M;
    int ab = 0, an = 0;
    size_t abase = 0;
    if (AMODE == 0) abase = (size_t)ar * K;
    else { ab = ar / N_; an = ar - ab*N_; }

    for (int k0 = 0; k0 < K; k0 += 16) {
        float4 av = make_float4(0.f,0.f,0.f,0.f);
        if (avalid) {
            int k = k0 + lk;
            if (AMODE == 0) av = *(const float4*)(A + abase + k);
            else {
                int l = k >> 6, d = k & 63;
                av = *(const float4*)(A + (((size_t)(ab*L_ + l)*N_ + an) << 6) + d);
            }
        }
        As[lk+0][lm]=av.x; As[lk+1][lm]=av.y; As[lk+2][lm]=av.z; As[lk+3][lm]=av.w;
        {
            int k = k0 + wk, j = col0 + wj;
            float4 wv;
            if (j + 3 < N) wv = *(const float4*)(W + (size_t)k*N + j);
            else {
                wv.x = (j   < N) ? W[(size_t)k*N + j  ] : 0.f;
                wv.y = (j+1 < N) ? W[(size_t)k*N + j+1] : 0.f;
                wv.z = (j+2 < N) ? W[(size_t)k*N + j+2] : 0.f;
                wv.w = 0.f;
            }
            Ws[wk][wj+0]=wv.x; Ws[wk][wj+1]=wv.y; Ws[wk][wj+2]=wv.z; Ws[wk][wj+3]=wv.w;
        }
        __syncthreads();
        #pragma unroll
        for (int kk = 0; kk < 16; ++kk) {
            const float4 a = *(const float4*)&As[kk][ty<<2];
            const float4 b = *(const float4*)&Ws[kk][tx<<2];
            float ar_[4] = {a.x,a.y,a.z,a.w};
            float br_[4] = {b.x,b.y,b.z,b.w};
            #pragma unroll
            for (int i = 0; i < 4; ++i)
                #pragma unroll
                for (int j = 0; j < 4; ++j)
                    acc[i][j] += ar_[i]*br_[j];
        }
        __syncthreads();
    }
    #pragma unroll
    for (int i = 0; i < 4; ++i) {
        int r = row0 + (ty<<2) + i;
        if (r >= M) continue;
        #pragma unroll
        for (int j = 0; j < 4; ++j) {
            int c = col0 + (tx<<2) + j;
            if (c >= N) continue;
            float v = acc[i][j];
            if (bias) v += bias[c];
            if (ADDTO) v += C[(size_t)r*N + c];
            if (RELU)  v = fmaxf(v, 0.f);
            if (CMODE == 0) C[(size_t)r*N + c] = v;
            else {
                int b = r / N_, n = r - (r/N_)*N_;
                C[(size_t)(b*L_ + c)*N_ + n] = v;
            }
        }
    }
}

// ============================ attention scores sc_s / sc_d ============================
__global__ void k_sc(const float* __restrict__ h, const float* __restrict__ as_,
                     const float* __restrict__ ad_, float* __restrict__ scs,
                     float* __restrict__ scd, int R)
{
    int r = blockIdx.x*256 + threadIdx.x;
    if (r >= R) return;
    const float* hr = h + (size_t)r*128;
    #pragma unroll
    for (int hh = 0; hh < 4; ++hh) {
        float ss = 0.f, sd = 0.f;
        #pragma unroll
        for (int k = 0; k < 32; ++k) {
            float hv = hr[hh*32 + k];
            ss += hv*as_[hh*32+k];
            sd += hv*ad_[hh*32+k];
        }
        scs[(size_t)r*4+hh] = ss;
        scd[(size_t)r*4+hh] = sd;
    }
}

// ============================ edge softmax: pass1 (leaky-relu + atomic max) ============
__device__ __forceinline__ unsigned enc_f(float x){
    unsigned u = __float_as_uint(x);
    return (u & 0x80000000u) ? ~u : (u | 0x80000000u);
}
__device__ __forceinline__ float dec_f(unsigned u){
    return (u & 0x80000000u) ? __uint_as_float(u & 0x7fffffffu) : __uint_as_float(~u);
}
__global__ void k_att1(const float* __restrict__ scs, const float* __restrict__ scd,
                       const int* __restrict__ ei, int E, int NN,
                       float* __restrict__ a_buf, unsigned* __restrict__ nmax)
{
    int idx = blockIdx.x*256 + threadIdx.x;
    if (idx >= B_*E) return;
    int b = idx / E, e = idx - b*E;
    int s = ei[e], tg = ei[E+e];
    const float* ps = scs + (size_t)(b*NN+s)*4;
    const float* pd = scd + (size_t)(b*NN+tg)*4;
    unsigned* pm = nmax + (size_t)(b*NN+tg)*4;
    float* pa = a_buf + (size_t)idx*4;
    #pragma unroll
    for (int hh = 0; hh < 4; ++hh) {
        float al = ps[hh] + pd[hh];
        al = al > 0.f ? al : 0.2f*al;
        pa[hh] = al;
        atomicMax(pm + hh, enc_f(al));
    }
}
__global__ void k_att2(const int* __restrict__ ei, int E, int NN,
                       float* __restrict__ a_buf, const unsigned* __restrict__ nmax,
                       float* __restrict__ nsum)
{
    int idx = blockIdx.x*256 + threadIdx.x;
    if (idx >= B_*E) return;
    int b = idx / E, e = idx - b*E;
    int tg = ei[E+e];
    const unsigned* pm = nmax + (size_t)(b*NN+tg)*4;
    float* ns = nsum + (size_t)(b*NN+tg)*4;
    float* pa = a_buf + (size_t)idx*4;
    #pragma unroll
    for (int hh = 0; hh < 4; ++hh) {
        float ex = expf(pa[hh] - dec_f(pm[hh]));
        pa[hh] = ex;
        atomicAdd(ns + hh, ex);
    }
}

// ============================ CSR build (target-indexed) ============================
__global__ void k_count(const int* __restrict__ ei, int E, int* __restrict__ counts){
    int e = blockIdx.x*256 + threadIdx.x;
    if (e < E) atomicAdd(&counts[ei[E + e]], 1);
}
__global__ void k_scan(const int* __restrict__ counts, int* __restrict__ off,
                       int* __restrict__ cur, int n)
{
    __shared__ int s[1024];
    int t = threadIdx.x;
    int v0 = (t < n) ? counts[t] : 0;
    s[t] = v0;
    __syncthreads();
    for (int o = 1; o < 1024; o <<= 1) {
        int v = (t >= o) ? s[t-o] : 0;
        __syncthreads();
        s[t] += v;
        __syncthreads();
    }
    if (t < n) {
        off[t+1] = s[t];
        cur[t] = s[t] - v0;
        if (t == 0) off[0] = 0;
    }
}
__global__ void k_fill(const int* __restrict__ ei, int E, int* __restrict__ cur,
                       int* __restrict__ lst){
    int e = blockIdx.x*256 + threadIdx.x;
    if (e < E) {
        int pos = atomicAdd(&cur[ei[E+e]], 1);
        lst[pos] = e;
    }
}

// ============================ GAT aggregation (CSR gather) ============================
template<bool USE_ATT>
__global__ void k_gather(const float* __restrict__ h, const float* __restrict__ a_buf,
                         const float* __restrict__ nsum, const float* __restrict__ att,
                         const int* __restrict__ ei, const int* __restrict__ off,
                         const int* __restrict__ lst, const float* __restrict__ bias,
                         float* __restrict__ out, int E, int NN)
{
    int bn = blockIdx.x;               // b*NN + n
    int b = bn / NN, n = bn - b*NN;
    int c = threadIdx.x;               // 0..127
    int hh = c >> 5;
    float rn = 1.f / nsum[(size_t)bn*4 + hh];
    int o0 = off[n], o1 = off[n+1];
    float acc = 0.f;
    for (int i = o0; i < o1; ++i) {
        int e = lst[i];
        float a = a_buf[((size_t)b*E + e)*4 + hh] * rn;
        if (USE_ATT) a *= att[(size_t)b*E + e];
        int s = ei[e];
        acc += a * h[((size_t)b*NN + s)*128 + c];
    }
    out[(size_t)bn*128 + c] = acc + bias[c];
}

// ======== fused extractor stage2: att = sigmoid(relu(relu(P[es]+Q[et])@W2+b2)@w3+b3) ========
__launch_bounds__(256)
__global__ void gemm_ext2(const float* __restrict__ P, const float* __restrict__ Q,
                          const float* __restrict__ W2, const float* __restrict__ b2,
                          const float* __restrict__ w3, const float* __restrict__ b3p,
                          const int* __restrict__ ei, float* __restrict__ att,
                          int Rtot, int E, int NN)
{
    __shared__ float As[16][64];
    __shared__ float Ws[16][128];
    __shared__ float red[16][64];
    const int t = threadIdx.x;
    const int ty = t >> 4, tx = t & 15;
    const int row0 = blockIdx.x << 6;
    const int lm = t >> 2, lk = (t & 3) << 2;
    const int wk = t >> 4, wj = (t & 15) << 3;
    const int r = row0 + lm;
    const bool valid = r < Rtot;
    const float *pr = P, *qr = Q;
    if (valid) {
        int b = r / E, e = r - b*E;
        pr = P + ((size_t)b*NN + ei[e])*512;
        qr = Q + ((size_t)b*NN + ei[E+e])*512;
    }
    float acc[4][8] = {};
    for (int k0 = 0; k0 < 512; k0 += 16) {
        float4 pv = make_float4(0,0,0,0), qv = make_float4(0,0,0,0);
        if (valid) {
            pv = *(const float4*)(pr + k0 + lk);
            qv = *(const float4*)(qr + k0 + lk);
        }
        As[lk+0][lm] = fmaxf(pv.x+qv.x, 0.f);
        As[lk+1][lm] = fmaxf(pv.y+qv.y, 0.f);
        As[lk+2][lm] = fmaxf(pv.z+qv.z, 0.f);
        As[lk+3][lm] = fmaxf(pv.w+qv.w, 0.f);
        {
            float4 w0 = *(const float4*)(W2 + (size_t)(k0+wk)*128 + wj);
            float4 w1 = *(const float4*)(W2 + (size_t)(k0+wk)*128 + wj + 4);
            Ws[wk][wj+0]=w0.x; Ws[wk][wj+1]=w0.y; Ws[wk][wj+2]=w0.z; Ws[wk][wj+3]=w0.w;
            Ws[wk][wj+4]=w1.x; Ws[wk][wj+5]=w1.y; Ws[wk][wj+6]=w1.z; Ws[wk][wj+7]=w1.w;
        }
        __syncthreads();
        #pragma unroll
        for (int kk = 0; kk < 16; ++kk) {
            const float4 a  = *(const float4*)&As[kk][ty<<2];
            const float4 b0 = *(const float4*)&Ws[kk][tx<<3];
            const float4 b1 = *(const float4*)&Ws[kk][(tx<<3)+4];
            float ar_[4] = {a.x,a.y,a.z,a.w};
            float br_[8] = {b0.x,b0.y,b0.z,b0.w,b1.x,b1.y,b1.z,b1.w};
            #pragma unroll
            for (int i = 0; i < 4; ++i)
                #pragma unroll
                for (int j = 0; j < 8; ++j)
                    acc[i][j] += ar_[i]*br_[j];
        }
        __syncthreads();
    }
    // epilogue: h2 = relu(acc + b2), partial logit = sum h2*w3
    float w3v[8], b2v[8];
    #pragma unroll
    for (int j = 0; j < 8; ++j) { int c = (tx<<3)+j; b2v[j]=b2[c]; w3v[j]=w3[c]; }
    #pragma unroll
    for (int i = 0; i < 4; ++i) {
        float s = 0.f;
        #pragma unroll
        for (int j = 0; j < 8; ++j) s += fmaxf(acc[i][j]+b2v[j], 0.f)*w3v[j];
        red[tx][(ty<<2)+i] = s;
    }
    __syncthreads();
    if (t < 64) {
        float s = 0.f;
        #pragma unroll
        for (int x = 0; x < 16; ++x) s += red[x][t];
        int rr = row0 + t;
        if (rr < Rtot) att[rr] = 1.f/(1.f + expf(-(s + b3p[0])));
    }
}

// ============================ temp_in: split-K over nodes ============================
__global__ void k_bias_fill(float* __restrict__ dst, const float* __restrict__ bias, int n){
    int i = blockIdx.x*256 + threadIdx.x;
    if (i < n) dst[i] = bias[i & 127];
}
__global__ void k_temp_in(const float* __restrict__ spa_back,  // [(b*883+n)*768 + l*64+d]
                          const float* __restrict__ Wt,        // [56512,128]
                          float* __restrict__ temp_in)         // [(b*12+l)*128 + c]
{
    int b  = blockIdx.y;
    int n0 = blockIdx.x * 32;
    int t  = threadIdx.x;
    int c  = t & 127;
    int lg = t >> 7;                    // 0/1 -> l in [lg*6, lg*6+6)
    float acc[6] = {};
    __shared__ float Asb[768];
    int nEnd = (n0 + 32 > N_) ? N_ : (n0 + 32);
    for (int n = n0; n < nEnd; ++n) {
        __syncthreads();
        const float* src = spa_back + ((size_t)(b*N_ + n))*LDM;
        for (int i = t; i < LDM; i += 256) Asb[i] = src[i];
        __syncthreads();
        const float* wp = Wt + ((size_t)n*64)*128 + c;
        for (int d = 0; d < 64; ++d) {
            float w = wp[(size_t)d*128];
            #pragma unroll
            for (int j = 0; j < 6; ++j)
                acc[j] += Asb[(lg*6+j)*64 + d] * w;
        }
    }
    #pragma unroll
    for (int j = 0; j < 6; ++j)
        atomicAdd(&temp_in[(size_t)(b*L_ + lg*6 + j)*128 + c], acc[j]);
}

// ============================ hid concat ============================
__global__ void k_hid(const float* __restrict__ ts_res, const float* __restrict__ ts_temp,
                      const float* __restrict__ node_emb, const float* __restrict__ tid_emb,
                      const float* __restrict__ diw_emb, const float* __restrict__ hist,
                      float* __restrict__ hid)
{
    int idx = blockIdx.x*256 + threadIdx.x;
    if (idx >= RBN*320) return;
    int r = idx / 320, c = idx - r*320;
    int b = r / N_, n = r - b*N_;
    float v;
    if (c < 64)        v = ts_res[(size_t)r*64 + c];
    else if (c < 128)  v = ts_temp[(size_t)r*64 + (c-64)];
    else if (c < 192)  v = node_emb[(size_t)n*64 + (c-128)];
    else if (c < 256) {
        int tid = (int)hist[((size_t)(b*L_ + (L_-1))*N_ + n)*3 + 1];
        v = tid_emb[(size_t)tid*64 + (c-192)];
    } else {
        int diw = (int)hist[((size_t)(b*L_ + (L_-1))*N_ + n)*3 + 2];
        v = diw_emb[(size_t)diw*64 + (c-256)];
    }
    hid[idx] = v;
}

// =====================================================================================
extern "C" void kernel_launch(void* const* d_in, const int* in_sizes, int n_in,
                              void* d_out, int out_size, void* d_ws, size_t ws_size,
                              hipStream_t stream)
{
    (void)in_sizes; (void)n_in; (void)out_size; (void)ws_size;
    const float* hist      = (const float*)d_in[0];
    const int*   ei_sp     = (const int*)  d_in[1];
    const int*   ei_tp     = (const int*)  d_in[2];
    const float* node_emb  = (const float*)d_in[3];
    const float* tid_emb   = (const float*)d_in[4];
    const float* diw_emb   = (const float*)d_in[5];
    const float* start_w   = (const float*)d_in[6];
    const float* start_b   = (const float*)d_in[7];
    const float* ts_w      = (const float*)d_in[8];
    const float* ts_b      = (const float*)d_in[9];
    const float* tr_spat_w = (const float*)d_in[10];
    const float* tr_spat_b = (const float*)d_in[11];
    const float* inv_spat_w= (const float*)d_in[12];
    const float* inv_spat_b= (const float*)d_in[13];
    const float* tr_temp_w = (const float*)d_in[14];
    const float* tr_temp_b = (const float*)d_in[15];
    const float* inv_temp_w= (const float*)d_in[16];
    const float* inv_temp_b= (const float*)d_in[17];
    const float* gat_sp_w  = (const float*)d_in[18];
    const float* gat_sp_as = (const float*)d_in[19];
    const float* gat_sp_ad = (const float*)d_in[20];
    const float* gat_sp_b  = (const float*)d_in[21];
    const float* ext_sp_w1 = (const float*)d_in[22];
    const float* ext_sp_b1 = (const float*)d_in[23];
    const float* ext_sp_w2 = (const float*)d_in[24];
    const float* ext_sp_b2 = (const float*)d_in[25];
    const float* ext_sp_w3 = (const float*)d_in[26];
    const float* ext_sp_b3 = (const float*)d_in[27];
    const float* gat_tp_w  = (const float*)d_in[28];
    const float* gat_tp_as = (const float*)d_in[29];
    const float* gat_tp_ad = (const float*)d_in[30];
    const float* gat_tp_b  = (const float*)d_in[31];
    const float* ext_tp_w1 = (const float*)d_in[32];
    const float* ext_tp_b1 = (const float*)d_in[33];
    const float* ext_tp_w2 = (const float*)d_in[34];
    const float* ext_tp_b2 = (const float*)d_in[35];
    const float* ext_tp_w3 = (const float*)d_in[36];
    const float* ext_tp_b3 = (const float*)d_in[37];
    const float* enc_w1    = (const float*)d_in[38];
    const float* enc_b1    = (const float*)d_in[39];
    const float* enc_w2    = (const float*)d_in[40];
    const float* enc_b2    = (const float*)d_in[41];
    const float* reg_w     = (const float*)d_in[42];
    const float* reg_b     = (const float*)d_in[43];
    float* out = (float*)d_out;

    // ---------------- workspace layout (all offsets 256B-aligned) ----------------
    size_t o = 0;
    char* wsb = (char*)d_ws;
    auto alloc = [&](size_t nfloats) -> float* {
        float* p = (float*)(wsb + o);
        o += ((nfloats + 63) & ~(size_t)63) * 4;
        return p;
    };
    float* R0      = alloc((size_t)RBN*LDM);   // res -> P_sp -> spa_back -> temp_back -> hid
    float* R1      = alloc((size_t)RBN*512);   // Q_sp -> enc_tmp
    float* ts_res  = alloc((size_t)RBN*64);
    float* spaX    = alloc((size_t)RBN*128);   // spa_in -> spa_out
    float* h_sp    = alloc((size_t)RBN*128);
    float* sc_s    = alloc((size_t)RBN*4);
    float* sc_d    = alloc((size_t)RBN*4);
    unsigned* nmax = (unsigned*)alloc((size_t)RBN*4);
    float* nsum    = alloc((size_t)RBN*4);
    float* a_buf   = alloc((size_t)B_*E_SP*4);
    float* att     = alloc((size_t)B_*E_SP);
    float* emb     = alloc((size_t)RBN*128);
    int*   csr     = (int*)alloc(17024);
    float* temp_in = alloc((size_t)RBL*128);
    float* h_tp    = alloc((size_t)RBL*128);
    float* tout_t  = alloc((size_t)RBL*128);
    float* P_t     = alloc((size_t)RBL*512);
    float* Q_t     = alloc((size_t)RBL*512);
    float* ts_temp = alloc((size_t)RBN*64);

    int* counts_sp = csr;
    int* off_sp    = csr + 883;
    int* cur_sp    = csr + 1767;
    int* list_sp   = csr + 2650;
    int* counts_tp = csr + 16778;
    int* off_tp    = csr + 16790;
    int* cur_tp    = csr + 16803;
    int* list_tp   = csr + 16815;

    // ---------------- CSR builds (same every call; edges are inputs) ----------------
    hipMemsetAsync(counts_sp, 0, 883*4, stream);
    k_count<<<cdiv_h(E_SP,256),256,0,stream>>>(ei_sp, E_SP, counts_sp);
    k_scan<<<1,1024,0,stream>>>(counts_sp, off_sp, cur_sp, 883);
    k_fill<<<cdiv_h(E_SP,256),256,0,stream>>>(ei_sp, E_SP, cur_sp, list_sp);
    hipMemsetAsync(counts_tp, 0, 12*4, stream);
    k_count<<<1,256,0,stream>>>(ei_tp, E_TP, counts_tp);
    k_scan<<<1,1024,0,stream>>>(counts_tp, off_tp, cur_tp, 12);
    k_fill<<<1,256,0,stream>>>(ei_tp, E_TP, cur_tp, list_tp);

    // ---------------- res / ts_res / spa_in ----------------
    k_res<<<cdiv_h(RBN*LDM,256),256,0,stream>>>(hist, start_w, start_b, R0);
    gemm_k<0,0,false,false><<<dim3(1,442),256,0,stream>>>(R0, ts_w, ts_b, ts_res, RBN, 64, LDM);
    gemm_k<0,0,false,false><<<dim3(2,442),256,0,stream>>>(R0, tr_spat_w, tr_spat_b, spaX, RBN, 128, LDM);

    // ---------------- spatial GAT (shared between both _gat calls) ----------------
    gemm_k<0,0,false,false><<<dim3(2,442),256,0,stream>>>(spaX, gat_sp_w, nullptr, h_sp, RBN, 128, 128);
    k_sc<<<cdiv_h(RBN,256),256,0,stream>>>(h_sp, gat_sp_as, gat_sp_ad, sc_s, sc_d, RBN);
    hipMemsetAsync(nmax, 0, (size_t)RBN*4*4, stream);
    hipMemsetAsync(nsum, 0, (size_t)RBN*4*4, stream);
    k_att1<<<cdiv_h(B_*E_SP,256),256,0,stream>>>(sc_s, sc_d, ei_sp, E_SP, N_, a_buf, nmax);
    k_att2<<<cdiv_h(B_*E_SP,256),256,0,stream>>>(ei_sp, E_SP, N_, a_buf, nmax, nsum);
    k_gather<false><<<RBN,128,0,stream>>>(h_sp, a_buf, nsum, nullptr, ei_sp, off_sp, list_sp,
                                          gat_sp_b, emb, E_SP, N_);
    // extractor: P = emb@W1a + b1 ; Q = emb@W1b ; att = sigmoid(MLP)
    gemm_k<0,0,false,false><<<dim3(8,442),256,0,stream>>>(emb, ext_sp_w1, ext_sp_b1, R0, RBN, 512, 128);
    gemm_k<0,0,false,false><<<dim3(8,442),256,0,stream>>>(emb, ext_sp_w1 + 128*512, nullptr, R1, RBN, 512, 128);
    gemm_ext2<<<cdiv_h(B_*E_SP,64),256,0,stream>>>(R0, R1, ext_sp_w2, ext_sp_b2, ext_sp_w3, ext_sp_b3,
                                                   ei_sp, att, B_*E_SP, E_SP, N_);
    k_gather<true><<<RBN,128,0,stream>>>(h_sp, a_buf, nsum, att, ei_sp, off_sp, list_sp,
                                         gat_sp_b, spaX, E_SP, N_);

    // ---------------- back-projection + temporal input ----------------
    gemm_k<0,0,false,false><<<dim3(12,442),256,0,stream>>>(spaX, inv_spat_w, inv_spat_b, R0, RBN, LDM, 128);
    k_bias_fill<<<cdiv_h(RBL*128,256),256,0,stream>>>(temp_in, tr_temp_b, RBL*128);
    k_temp_in<<<dim3(28,B_),256,0,stream>>>(R0, tr_temp_w, temp_in);

    // ---------------- temporal GAT ----------------
    gemm_k<0,0,false,false><<<dim3(2,6),256,0,stream>>>(temp_in, gat_tp_w, nullptr, h_tp, RBL, 128, 128);
    k_sc<<<cdiv_h(RBL,256),256,0,stream>>>(h_tp, gat_tp_as, gat_tp_ad, sc_s, sc_d, RBL);
    hipMemsetAsync(nmax, 0, (size_t)RBL*4*4, stream);
    hipMemsetAsync(nsum, 0, (size_t)RBL*4*4, stream);
    k_att1<<<cdiv_h(B_*E_TP,256),256,0,stream>>>(sc_s, sc_d, ei_tp, E_TP, NT_, a_buf, nmax);
    k_att2<<<cdiv_h(B_*E_TP,256),256,0,stream>>>(ei_tp, E_TP, NT_, a_buf, nmax, nsum);
    k_gather<false><<<RBL,128,0,stream>>>(h_tp, a_buf, nsum, nullptr, ei_tp, off_tp, list_tp,
                                          gat_tp_b, emb, E_TP, NT_);
    gemm_k<0,0,false,false><<<dim3(8,6),256,0,stream>>>(emb, ext_tp_w1, ext_tp_b1, P_t, RBL, 512, 128);
    gemm_k<0,0,false,false><<<dim3(8,6),256,0,stream>>>(emb, ext_tp_w1 + 128*512, nullptr, Q_t, RBL, 512, 128);
    gemm_ext2<<<cdiv_h(B_*E_TP,64),256,0,stream>>>(P_t, Q_t, ext_tp_w2, ext_tp_b2, ext_tp_w3, ext_tp_b3,
                                                   ei_tp, att, B_*E_TP, E_TP, NT_);
    k_gather<true><<<RBL,128,0,stream>>>(h_tp, a_buf, nsum, att, ei_tp, off_tp, list_tp,
                                         gat_tp_b, tout_t, E_TP, NT_);

    // ---------------- temporal back-projection + ts_temp ----------------
    gemm_k<0,0,false,false><<<dim3(883,6),256,0,stream>>>(tout_t, inv_temp_w, inv_temp_b, R0, RBL, NDM, 128);
    gemm_k<1,0,false,false><<<dim3(1,442),256,0,stream>>>(R0, ts_w, ts_b, ts_temp, RBN, 64, LDM);

    // ---------------- concat + residual MLP encoder + regression head ----------------
    k_hid<<<cdiv_h(RBN*320,256),256,0,stream>>>(ts_res, ts_temp, node_emb, tid_emb, diw_emb, hist, R0);
    for (int i = 0; i < 3; ++i) {
        gemm_k<0,0,true,false><<<dim3(5,442),256,0,stream>>>(R0, enc_w1 + (size_t)i*320*320,
                                                             enc_b1 + i*320, R1, RBN, 320, 320);
        gemm_k<0,0,false,true><<<dim3(5,442),256,0,stream>>>(R1, enc_w2 + (size_t)i*320*320,
                                                             enc_b2 + i*320, R0, RBN, 320, 320);
    }
    gemm_k<0,1,false,false><<<dim3(1,442),256,0,stream>>>(R0, reg_w, reg_b, out, RBN, 12, 320);
}

// Round 2
// 2078.504 us; speedup vs baseline: 1.3619x; 1.3619x over previous
//
#include <hip/hip_runtime.h>
#include <hip/hip_bf16.h>
#include <cstdint>
#include <cstddef>

#define B_   32
#define L_   12
#define N_   883
#define DM_  64
#define E_SP 14128
#define E_TP 144
#define NT_  12
#define RBN  28256      // B*N
#define RBL  384        // B*L
#define LDM  768        // L*DM
#define NDM  56512      // N*DM

static inline int cdiv_h(int a, int b){ return (a+b-1)/b; }

// bf16 round-to-nearest-even from float
__device__ __forceinline__ ushort f2bf(float f){
    unsigned u = __float_as_uint(f);
    unsigned lsb = (u >> 16) & 1u;
    u += 0x7fffu + lsb;
    return (ushort)(u >> 16);
}
__device__ __forceinline__ float bf2f(ushort h){
    return __uint_as_float(((unsigned)h) << 16);
}

typedef __bf16 bf16x8 __attribute__((ext_vector_type(8)));
typedef float  f32x4  __attribute__((ext_vector_type(4)));
union BF8 { bf16x8 v; ushort u[8]; int4 i; };

// ============================ res: X = hist @ start_w + start_b ============================
__global__ void k_res(const float* __restrict__ hist, const float* __restrict__ sw,
                      const float* __restrict__ sb, float* __restrict__ res)
{
    int idx = blockIdx.x*256 + threadIdx.x;
    if (idx >= RBN*LDM) return;
    int r = idx / LDM, col = idx - r*LDM;
    int b = r / N_, n = r - b*N_;
    int l = col >> 6, d = col & 63;
    const float* hp = hist + ((size_t)(b*L_ + l)*N_ + n)*3;
    res[idx] = hp[0]*sw[d] + hp[1]*sw[64+d] + hp[2]*sw[128+d] + sb[d];
}

// ============================ generic fp32 GEMM: C = act(A@W + bias [+C]) =================
// AMODE 0: A[r*K+k].  AMODE 1: r=(b*883+n), k=(l*64+d), A addr = ((b*12+l)*883+n)*64+d.
// CMODE 0: C[r*N+c].  CMODE 1: C addr = (b*12+c)*883+n.  OUTBF: store bf16 (ushort) instead of f32.
template<int AMODE, int CMODE, bool RELU, bool ADDTO, bool OUTBF=false>
__launch_bounds__(256)
__global__ void gemm_k(const float* __restrict__ A, const float* __restrict__ W,
                       const float* __restrict__ bias, float* __restrict__ C,
                       int M, int N, int K)
{
    __shared__ float As[16][64];
    __shared__ float Ws[16][64];
    const int t  = threadIdx.x;
    const int ty = t >> 4, tx = t & 15;
    const int row0 = blockIdx.y << 6, col0 = blockIdx.x << 6;
    const int lm = t >> 2, lk = (t & 3) << 2;
    const int wk = t >> 4, wj = (t & 15) << 2;
    float acc[4][4] = {};
    const int ar = row0 + lm;
    const bool avalid = ar < M;
    int ab = 0, an = 0;
    size_t abase = 0;
    if (AMODE == 0) abase = (size_t)ar * K;
    else { ab = ar / N_; an = ar - ab*N_; }

    for (int k0 = 0; k0 < K; k0 += 16) {
        float4 av = make_float4(0.f,0.f,0.f,0.f);
        if (avalid) {
            int k = k0 + lk;
            if (AMODE == 0) av = *(const float4*)(A + abase + k);
            else {
                int l = k >> 6, d = k & 63;
                av = *(const float4*)(A + (((size_t)(ab*L_ + l)*N_ + an) << 6) + d);
            }
        }
        As[lk+0][lm]=av.x; As[lk+1][lm]=av.y; As[lk+2][lm]=av.z; As[lk+3][lm]=av.w;
        {
            int k = k0 + wk, j = col0 + wj;
            float4 wv;
            if (j + 3 < N) wv = *(const float4*)(W + (size_t)k*N + j);
            else {
                wv.x = (j   < N) ? W[(size_t)k*N + j  ] : 0.f;
                wv.y = (j+1 < N) ? W[(size_t)k*N + j+1] : 0.f;
                wv.z = (j+2 < N) ? W[(size_t)k*N + j+2] : 0.f;
                wv.w = 0.f;
            }
            Ws[wk][wj+0]=wv.x; Ws[wk][wj+1]=wv.y; Ws[wk][wj+2]=wv.z; Ws[wk][wj+3]=wv.w;
        }
        __syncthreads();
        #pragma unroll
        for (int kk = 0; kk < 16; ++kk) {
            const float4 a = *(const float4*)&As[kk][ty<<2];
            const float4 b = *(const float4*)&Ws[kk][tx<<2];
            float ar_[4] = {a.x,a.y,a.z,a.w};
            float br_[4] = {b.x,b.y,b.z,b.w};
            #pragma unroll
            for (int i = 0; i < 4; ++i)
                #pragma unroll
                for (int j = 0; j < 4; ++j)
                    acc[i][j] += ar_[i]*br_[j];
        }
        __syncthreads();
    }
    #pragma unroll
    for (int i = 0; i < 4; ++i) {
        int r = row0 + (ty<<2) + i;
        if (r >= M) continue;
        #pragma unroll
        for (int j = 0; j < 4; ++j) {
            int c = col0 + (tx<<2) + j;
            if (c >= N) continue;
            float v = acc[i][j];
            if (bias) v += bias[c];
            if (ADDTO) v += C[(size_t)r*N + c];
            if (RELU)  v = fmaxf(v, 0.f);
            if (OUTBF) {
                ((ushort*)C)[(size_t)r*N + c] = f2bf(v);
            } else if (CMODE == 0) {
                C[(size_t)r*N + c] = v;
            } else {
                int b = r / N_, n = r - (r/N_)*N_;
                C[(size_t)(b*L_ + c)*N_ + n] = v;
            }
        }
    }
}

// ============================ attention scores sc_s / sc_d ============================
__global__ void k_sc(const float* __restrict__ h, const float* __restrict__ as_,
                     const float* __restrict__ ad_, float* __restrict__ scs,
                     float* __restrict__ scd, int R)
{
    int r = blockIdx.x*256 + threadIdx.x;
    if (r >= R) return;
    const float* hr = h + (size_t)r*128;
    #pragma unroll
    for (int hh = 0; hh < 4; ++hh) {
        float ss = 0.f, sd = 0.f;
        #pragma unroll
        for (int k = 0; k < 32; ++k) {
            float hv = hr[hh*32 + k];
            ss += hv*as_[hh*32+k];
            sd += hv*ad_[hh*32+k];
        }
        scs[(size_t)r*4+hh] = ss;
        scd[(size_t)r*4+hh] = sd;
    }
}

// ============================ edge softmax ============================
__device__ __forceinline__ unsigned enc_f(float x){
    unsigned u = __float_as_uint(x);
    return (u & 0x80000000u) ? ~u : (u | 0x80000000u);
}
__device__ __forceinline__ float dec_f(unsigned u){
    return (u & 0x80000000u) ? __uint_as_float(u & 0x7fffffffu) : __uint_as_float(~u);
}
__global__ void k_att1(const float* __restrict__ scs, const float* __restrict__ scd,
                       const int* __restrict__ ei, int E, int NN,
                       float* __restrict__ a_buf, unsigned* __restrict__ nmax)
{
    int idx = blockIdx.x*256 + threadIdx.x;
    if (idx >= B_*E) return;
    int b = idx / E, e = idx - b*E;
    int s = ei[e], tg = ei[E+e];
    const float* ps = scs + (size_t)(b*NN+s)*4;
    const float* pd = scd + (size_t)(b*NN+tg)*4;
    unsigned* pm = nmax + (size_t)(b*NN+tg)*4;
    float* pa = a_buf + (size_t)idx*4;
    #pragma unroll
    for (int hh = 0; hh < 4; ++hh) {
        float al = ps[hh] + pd[hh];
        al = al > 0.f ? al : 0.2f*al;
        pa[hh] = al;
        atomicMax(pm + hh, enc_f(al));
    }
}
__global__ void k_att2(const int* __restrict__ ei, int E, int NN,
                       float* __restrict__ a_buf, const unsigned* __restrict__ nmax,
                       float* __restrict__ nsum)
{
    int idx = blockIdx.x*256 + threadIdx.x;
    if (idx >= B_*E) return;
    int b = idx / E, e = idx - b*E;
    int tg = ei[E+e];
    const unsigned* pm = nmax + (size_t)(b*NN+tg)*4;
    float* ns = nsum + (size_t)(b*NN+tg)*4;
    float* pa = a_buf + (size_t)idx*4;
    #pragma unroll
    for (int hh = 0; hh < 4; ++hh) {
        float ex = expf(pa[hh] - dec_f(pm[hh]));
        pa[hh] = ex;
        atomicAdd(ns + hh, ex);
    }
}

// ============================ CSR build (target-indexed) ============================
__global__ void k_count(const int* __restrict__ ei, int E, int* __restrict__ counts){
    int e = blockIdx.x*256 + threadIdx.x;
    if (e < E) atomicAdd(&counts[ei[E + e]], 1);
}
__global__ void k_scan(const int* __restrict__ counts, int* __restrict__ off,
                       int* __restrict__ cur, int n)
{
    __shared__ int s[1024];
    int t = threadIdx.x;
    int v0 = (t < n) ? counts[t] : 0;
    s[t] = v0;
    __syncthreads();
    for (int o = 1; o < 1024; o <<= 1) {
        int v = (t >= o) ? s[t-o] : 0;
        __syncthreads();
        s[t] += v;
        __syncthreads();
    }
    if (t < n) {
        off[t+1] = s[t];
        cur[t] = s[t] - v0;
        if (t == 0) off[0] = 0;
    }
}
__global__ void k_fill(const int* __restrict__ ei, int E, int* __restrict__ cur,
                       int* __restrict__ lst){
    int e = blockIdx.x*256 + threadIdx.x;
    if (e < E) {
        int pos = atomicAdd(&cur[ei[E+e]], 1);
        lst[pos] = e;
    }
}

// ============================ GAT aggregation (CSR gather) ============================
template<bool USE_ATT>
__global__ void k_gather(const float* __restrict__ h, const float* __restrict__ a_buf,
                         const float* __restrict__ nsum, const float* __restrict__ att,
                         const int* __restrict__ ei, const int* __restrict__ off,
                         const int* __restrict__ lst, const float* __restrict__ bias,
                         float* __restrict__ out, int E, int NN)
{
    int bn = blockIdx.x;
    int b = bn / NN, n = bn - b*NN;
    int c = threadIdx.x;
    int hh = c >> 5;
    float rn = 1.f / nsum[(size_t)bn*4 + hh];
    int o0 = off[n], o1 = off[n+1];
    float acc = 0.f;
    for (int i = o0; i < o1; ++i) {
        int e = lst[i];
        float a = a_buf[((size_t)b*E + e)*4 + hh] * rn;
        if (USE_ATT) a *= att[(size_t)b*E + e];
        int s = ei[e];
        acc += a * h[((size_t)b*NN + s)*128 + c];
    }
    out[(size_t)bn*128 + c] = acc + bias[c];
}

// ============================ W2 -> bf16 transposed [col][k] ============================
__global__ void k_prepW2(const float* __restrict__ W2, ushort* __restrict__ W2T)
{
    int idx = blockIdx.x*256 + threadIdx.x;   // 512*128
    if (idx >= 512*128) return;
    int k = idx >> 7, c = idx & 127;
    W2T[(size_t)c*512 + k] = f2bf(W2[idx]);
}

// ======== MFMA fused extractor stage2: att = sigmoid(relu(relu(P[es]+Q[et])@W2+b2)@w3+b3) ===
// P,Q: bf16 [rows][512]. W2T: bf16 [128 cols][512 k]. 64 edge-rows per block, 4 waves.
// mfma_f32_16x16x32_bf16: A[m=lane&15][k=(lane>>4)*8+j], B[k=(lane>>4)*8+j][n=lane&15],
// C/D: col=lane&15, row=(lane>>4)*4+reg   [m89-verified layouts]
__launch_bounds__(256)
__global__ void ext2_mfma(const ushort* __restrict__ P, const ushort* __restrict__ Q,
                          const ushort* __restrict__ W2T, const float* __restrict__ b2,
                          const float* __restrict__ w3, const float* __restrict__ b3p,
                          const int* __restrict__ ei, float* __restrict__ att,
                          int E, int NN)
{
    __shared__ ushort Bs[128*72];          // [col][k], col stride 72 (144B, 16B-aligned)
    const int t  = threadIdx.x;
    const int wv = t >> 6, l = t & 63;
    const int row0 = blockIdx.x*64 + wv*16;
    const int lr = l & 15, lk = l >> 4;

    int r = row0 + lr;
    int b = r / E, e = r - b*E;
    const ushort* pr = P + ((size_t)b*NN + ei[e])*512 + lk*8;
    const ushort* qr = Q + ((size_t)b*NN + ei[E+e])*512 + lk*8;

    f32x4 acc[8] = {};
    for (int kc = 0; kc < 16; ++kc) {
        __syncthreads();
        #pragma unroll
        for (int i = 0; i < 2; ++i) {
            int it = t + i*256;            // [0,512)
            int c = it >> 2, part = it & 3;
            *(int4*)&Bs[c*72 + part*8] = *(const int4*)&W2T[(size_t)c*512 + kc*32 + part*8];
        }
        BF8 af;
        BF8 pu, qu;
        pu.i = *(const int4*)(pr + kc*32);
        qu.i = *(const int4*)(qr + kc*32);
        #pragma unroll
        for (int j = 0; j < 8; ++j)
            af.u[j] = f2bf(fmaxf(bf2f(pu.u[j]) + bf2f(qu.u[j]), 0.f));
        __syncthreads();
        #pragma unroll
        for (int ct = 0; ct < 8; ++ct) {
            BF8 bfm;
            bfm.v = *(const bf16x8*)&Bs[(ct*16 + lr)*72 + lk*8];
            acc[ct] = __builtin_amdgcn_mfma_f32_16x16x32_bf16(af.v, bfm.v, acc[ct], 0, 0, 0);
        }
    }
    // epilogue: h2 = relu(acc + b2[col]); partial logit per row = sum_col h2*w3[col]
    float part[4] = {0.f,0.f,0.f,0.f};
    #pragma unroll
    for (int ct = 0; ct < 8; ++ct) {
        int c = ct*16 + lr;
        float b2v = b2[c], w3v = w3[c];
        #pragma unroll
        for (int g = 0; g < 4; ++g)
            part[g] += fmaxf(acc[ct][g] + b2v, 0.f) * w3v;
    }
    #pragma unroll
    for (int m = 1; m < 16; m <<= 1)
        #pragma unroll
        for (int g = 0; g < 4; ++g)
            part[g] += __shfl_xor(part[g], m, 64);
    if (lr == 0) {
        float b3 = b3p[0];
        #pragma unroll
        for (int g = 0; g < 4; ++g) {
            int rr = row0 + lk*4 + g;
            att[rr] = 1.f/(1.f + expf(-(part[g] + b3)));
        }
    }
}

// ============================ temp_in: split-K over nodes ============================
__global__ void k_bias_fill(float* __restrict__ dst, const float* __restrict__ bias, int n){
    int i = blockIdx.x*256 + threadIdx.x;
    if (i < n) dst[i] = bias[i & 127];
}
__global__ void k_temp_in(const float* __restrict__ spa_back,
                          const float* __restrict__ Wt,
                          float* __restrict__ temp_in)
{
    int b  = blockIdx.y;
    int n0 = blockIdx.x * 32;
    int t  = threadIdx.x;
    int c  = t & 127;
    int lg = t >> 7;
    float acc[6] = {};
    __shared__ float Asb[768];
    int nEnd = (n0 + 32 > N_) ? N_ : (n0 + 32);
    for (int n = n0; n < nEnd; ++n) {
        __syncthreads();
        const float* src = spa_back + ((size_t)(b*N_ + n))*LDM;
        for (int i = t; i < LDM; i += 256) Asb[i] = src[i];
        __syncthreads();
        const float* wp = Wt + ((size_t)n*64)*128 + c;
        for (int d = 0; d < 64; ++d) {
            float w = wp[(size_t)d*128];
            #pragma unroll
            for (int j = 0; j < 6; ++j)
                acc[j] += Asb[(lg*6+j)*64 + d] * w;
        }
    }
    #pragma unroll
    for (int j = 0; j < 6; ++j)
        atomicAdd(&temp_in[(size_t)(b*L_ + lg*6 + j)*128 + c], acc[j]);
}

// ============================ hid concat ============================
__global__ void k_hid(const float* __restrict__ ts_res, const float* __restrict__ ts_temp,
                      const float* __restrict__ node_emb, const float* __restrict__ tid_emb,
                      const float* __restrict__ diw_emb, const float* __restrict__ hist,
                      float* __restrict__ hid)
{
    int idx = blockIdx.x*256 + threadIdx.x;
    if (idx >= RBN*320) return;
    int r = idx / 320, c = idx - r*320;
    int b = r / N_, n = r - b*N_;
    float v;
    if (c < 64)        v = ts_res[(size_t)r*64 + c];
    else if (c < 128)  v = ts_temp[(size_t)r*64 + (c-64)];
    else if (c < 192)  v = node_emb[(size_t)n*64 + (c-128)];
    else if (c < 256) {
        int tid = (int)hist[((size_t)(b*L_ + (L_-1))*N_ + n)*3 + 1];
        v = tid_emb[(size_t)tid*64 + (c-192)];
    } else {
        int diw = (int)hist[((size_t)(b*L_ + (L_-1))*N_ + n)*3 + 2];
        v = diw_emb[(size_t)diw*64 + (c-256)];
    }
    hid[idx] = v;
}

// =====================================================================================
extern "C" void kernel_launch(void* const* d_in, const int* in_sizes, int n_in,
                              void* d_out, int out_size, void* d_ws, size_t ws_size,
                              hipStream_t stream)
{
    (void)in_sizes; (void)n_in; (void)out_size; (void)ws_size;
    const float* hist      = (const float*)d_in[0];
    const int*   ei_sp     = (const int*)  d_in[1];
    const int*   ei_tp     = (const int*)  d_in[2];
    const float* node_emb  = (const float*)d_in[3];
    const float* tid_emb   = (const float*)d_in[4];
    const float* diw_emb   = (const float*)d_in[5];
    const float* start_w   = (const float*)d_in[6];
    const float* start_b   = (const float*)d_in[7];
    const float* ts_w      = (const float*)d_in[8];
    const float* ts_b      = (const float*)d_in[9];
    const float* tr_spat_w = (const float*)d_in[10];
    const float* tr_spat_b = (const float*)d_in[11];
    const float* inv_spat_w= (const float*)d_in[12];
    const float* inv_spat_b= (const float*)d_in[13];
    const float* tr_temp_w = (const float*)d_in[14];
    const float* tr_temp_b = (const float*)d_in[15];
    const float* inv_temp_w= (const float*)d_in[16];
    const float* inv_temp_b= (const float*)d_in[17];
    const float* gat_sp_w  = (const float*)d_in[18];
    const float* gat_sp_as = (const float*)d_in[19];
    const float* gat_sp_ad = (const float*)d_in[20];
    const float* gat_sp_b  = (const float*)d_in[21];
    const float* ext_sp_w1 = (const float*)d_in[22];
    const float* ext_sp_b1 = (const float*)d_in[23];
    const float* ext_sp_w2 = (const float*)d_in[24];
    const float* ext_sp_b2 = (const float*)d_in[25];
    const float* ext_sp_w3 = (const float*)d_in[26];
    const float* ext_sp_b3 = (const float*)d_in[27];
    const float* gat_tp_w  = (const float*)d_in[28];
    const float* gat_tp_as = (const float*)d_in[29];
    const float* gat_tp_ad = (const float*)d_in[30];
    const float* gat_tp_b  = (const float*)d_in[31];
    const float* ext_tp_w1 = (const float*)d_in[32];
    const float* ext_tp_b1 = (const float*)d_in[33];
    const float* ext_tp_w2 = (const float*)d_in[34];
    const float* ext_tp_b2 = (const float*)d_in[35];
    const float* ext_tp_w3 = (const float*)d_in[36];
    const float* ext_tp_b3 = (const float*)d_in[37];
    const float* enc_w1    = (const float*)d_in[38];
    const float* enc_b1    = (const float*)d_in[39];
    const float* enc_w2    = (const float*)d_in[40];
    const float* enc_b2    = (const float*)d_in[41];
    const float* reg_w     = (const float*)d_in[42];
    const float* reg_b     = (const float*)d_in[43];
    float* out = (float*)d_out;

    // ---------------- workspace layout ----------------
    size_t o = 0;
    char* wsb = (char*)d_ws;
    auto alloc = [&](size_t nfloats) -> float* {
        float* p = (float*)(wsb + o);
        o += ((nfloats + 63) & ~(size_t)63) * 4;
        return p;
    };
    float* R0      = alloc((size_t)RBN*LDM);   // res -> P_sp(bf16) -> spa_back -> temp_back -> hid
    float* R1      = alloc((size_t)RBN*512);   // Q_sp(bf16) -> enc_tmp
    float* ts_res  = alloc((size_t)RBN*64);
    float* spaX    = alloc((size_t)RBN*128);
    float* h_sp    = alloc((size_t)RBN*128);
    float* sc_s    = alloc((size_t)RBN*4);
    float* sc_d    = alloc((size_t)RBN*4);
    unsigned* nmax = (unsigned*)alloc((size_t)RBN*4);
    float* nsum    = alloc((size_t)RBN*4);
    float* a_buf   = alloc((size_t)B_*E_SP*4);
    float* att     = alloc((size_t)B_*E_SP);
    float* emb     = alloc((size_t)RBN*128);
    int*   csr     = (int*)alloc(17024);
    float* temp_in = alloc((size_t)RBL*128);
    float* h_tp    = alloc((size_t)RBL*128);
    float* tout_t  = alloc((size_t)RBL*128);
    float* P_t     = alloc((size_t)RBL*512);   // bf16 (half used)
    float* Q_t     = alloc((size_t)RBL*512);   // bf16 (half used)
    float* ts_temp = alloc((size_t)RBN*64);
    ushort* W2T_sp = (ushort*)alloc(32768);    // 128x512 bf16
    ushort* W2T_tp = (ushort*)alloc(32768);

    int* counts_sp = csr;
    int* off_sp    = csr + 883;
    int* cur_sp    = csr + 1767;
    int* list_sp   = csr + 2650;
    int* counts_tp = csr + 16778;
    int* off_tp    = csr + 16790;
    int* cur_tp    = csr + 16803;
    int* list_tp   = csr + 16815;

    // ---------------- CSR builds + weight prep ----------------
    hipMemsetAsync(counts_sp, 0, 883*4, stream);
    k_count<<<cdiv_h(E_SP,256),256,0,stream>>>(ei_sp, E_SP, counts_sp);
    k_scan<<<1,1024,0,stream>>>(counts_sp, off_sp, cur_sp, 883);
    k_fill<<<cdiv_h(E_SP,256),256,0,stream>>>(ei_sp, E_SP, cur_sp, list_sp);
    hipMemsetAsync(counts_tp, 0, 12*4, stream);
    k_count<<<1,256,0,stream>>>(ei_tp, E_TP, counts_tp);
    k_scan<<<1,1024,0,stream>>>(counts_tp, off_tp, cur_tp, 12);
    k_fill<<<1,256,0,stream>>>(ei_tp, E_TP, cur_tp, list_tp);
    k_prepW2<<<cdiv_h(512*128,256),256,0,stream>>>(ext_sp_w2, W2T_sp);
    k_prepW2<<<cdiv_h(512*128,256),256,0,stream>>>(ext_tp_w2, W2T_tp);

    // ---------------- res / ts_res / spa_in ----------------
    k_res<<<cdiv_h(RBN*LDM,256),256,0,stream>>>(hist, start_w, start_b, R0);
    gemm_k<0,0,false,false><<<dim3(1,442),256,0,stream>>>(R0, ts_w, ts_b, ts_res, RBN, 64, LDM);
    gemm_k<0,0,false,false><<<dim3(2,442),256,0,stream>>>(R0, tr_spat_w, tr_spat_b, spaX, RBN, 128, LDM);

    // ---------------- spatial GAT ----------------
    gemm_k<0,0,false,false><<<dim3(2,442),256,0,stream>>>(spaX, gat_sp_w, nullptr, h_sp, RBN, 128, 128);
    k_sc<<<cdiv_h(RBN,256),256,0,stream>>>(h_sp, gat_sp_as, gat_sp_ad, sc_s, sc_d, RBN);
    hipMemsetAsync(nmax, 0, (size_t)RBN*4*4, stream);
    hipMemsetAsync(nsum, 0, (size_t)RBN*4*4, stream);
    k_att1<<<cdiv_h(B_*E_SP,256),256,0,stream>>>(sc_s, sc_d, ei_sp, E_SP, N_, a_buf, nmax);
    k_att2<<<cdiv_h(B_*E_SP,256),256,0,stream>>>(ei_sp, E_SP, N_, a_buf, nmax, nsum);
    k_gather<false><<<RBN,128,0,stream>>>(h_sp, a_buf, nsum, nullptr, ei_sp, off_sp, list_sp,
                                          gat_sp_b, emb, E_SP, N_);
    // extractor: P = emb@W1a + b1 (bf16); Q = emb@W1b (bf16); att = sigmoid(MLP) via MFMA
    gemm_k<0,0,false,false,true><<<dim3(8,442),256,0,stream>>>(emb, ext_sp_w1, ext_sp_b1, R0, RBN, 512, 128);
    gemm_k<0,0,false,false,true><<<dim3(8,442),256,0,stream>>>(emb, ext_sp_w1 + 128*512, nullptr, R1, RBN, 512, 128);
    ext2_mfma<<<(B_*E_SP)/64,256,0,stream>>>((const ushort*)R0, (const ushort*)R1, W2T_sp,
                                             ext_sp_b2, ext_sp_w3, ext_sp_b3, ei_sp, att, E_SP, N_);
    k_gather<true><<<RBN,128,0,stream>>>(h_sp, a_buf, nsum, att, ei_sp, off_sp, list_sp,
                                         gat_sp_b, spaX, E_SP, N_);

    // ---------------- back-projection + temporal input ----------------
    gemm_k<0,0,false,false><<<dim3(12,442),256,0,stream>>>(spaX, inv_spat_w, inv_spat_b, R0, RBN, LDM, 128);
    k_bias_fill<<<cdiv_h(RBL*128,256),256,0,stream>>>(temp_in, tr_temp_b, RBL*128);
    k_temp_in<<<dim3(28,B_),256,0,stream>>>(R0, tr_temp_w, temp_in);

    // ---------------- temporal GAT ----------------
    gemm_k<0,0,false,false><<<dim3(2,6),256,0,stream>>>(temp_in, gat_tp_w, nullptr, h_tp, RBL, 128, 128);
    k_sc<<<cdiv_h(RBL,256),256,0,stream>>>(h_tp, gat_tp_as, gat_tp_ad, sc_s, sc_d, RBL);
    hipMemsetAsync(nmax, 0, (size_t)RBL*4*4, stream);
    hipMemsetAsync(nsum, 0, (size_t)RBL*4*4, stream);
    k_att1<<<cdiv_h(B_*E_TP,256),256,0,stream>>>(sc_s, sc_d, ei_tp, E_TP, NT_, a_buf, nmax);
    k_att2<<<cdiv_h(B_*E_TP,256),256,0,stream>>>(ei_tp, E_TP, NT_, a_buf, nmax, nsum);
    k_gather<false><<<RBL,128,0,stream>>>(h_tp, a_buf, nsum, nullptr, ei_tp, off_tp, list_tp,
                                          gat_tp_b, emb, E_TP, NT_);
    gemm_k<0,0,false,false,true><<<dim3(8,6),256,0,stream>>>(emb, ext_tp_w1, ext_tp_b1, P_t, RBL, 512, 128);
    gemm_k<0,0,false,false,true><<<dim3(8,6),256,0,stream>>>(emb, ext_tp_w1 + 128*512, nullptr, Q_t, RBL, 512, 128);
    ext2_mfma<<<(B_*E_TP)/64,256,0,stream>>>((const ushort*)P_t, (const ushort*)Q_t, W2T_tp,
                                             ext_tp_b2, ext_tp_w3, ext_tp_b3, ei_tp, att, E_TP, NT_);
    k_gather<true><<<RBL,128,0,stream>>>(h_tp, a_buf, nsum, att, ei_tp, off_tp, list_tp,
                                         gat_tp_b, tout_t, E_TP, NT_);

    // ---------------- temporal back-projection + ts_temp ----------------
    gemm_k<0,0,false,false><<<dim3(883,6),256,0,stream>>>(tout_t, inv_temp_w, inv_temp_b, R0, RBL, NDM, 128);
    gemm_k<1,0,false,false><<<dim3(1,442),256,0,stream>>>(R0, ts_w, ts_b, ts_temp, RBN, 64, LDM);

    // ---------------- concat + residual MLP encoder + regression head ----------------
    k_hid<<<cdiv_h(RBN*320,256),256,0,stream>>>(ts_res, ts_temp, node_emb, tid_emb, diw_emb, hist, R0);
    for (int i = 0; i < 3; ++i) {
        gemm_k<0,0,true,false><<<dim3(5,442),256,0,stream>>>(R0, enc_w1 + (size_t)i*320*320,
                                                             enc_b1 + i*320, R1, RBN, 320, 320);
        gemm_k<0,0,false,true><<<dim3(5,442),256,0,stream>>>(R1, enc_w2 + (size_t)i*320*320,
                                                             enc_b2 + i*320, R0, RBN, 320, 320);
    }
    gemm_k<0,1,false,false><<<dim3(1,442),256,0,stream>>>(R0, reg_w, reg_b, out, RBN, 12, 320);
}

// Round 3
// 1790.048 us; speedup vs baseline: 1.5813x; 1.1611x over previous
//
#include <hip/hip_runtime.h>
#include <hip/hip_bf16.h>
#include <cstdint>
#include <cstddef>

#define B_   32
#define L_   12
#define N_   883
#define DM_  64
#define E_SP 14128
#define E_TP 144
#define NT_  12
#define RBN  28256      // B*N
#define RBL  384        // B*L
#define LDM  768        // L*DM
#define NDM  56512      // N*DM

static inline int cdiv_h(int a, int b){ return (a+b-1)/b; }

// bf16 round-to-nearest-even from float
__device__ __forceinline__ ushort f2bf(float f){
    unsigned u = __float_as_uint(f);
    unsigned lsb = (u >> 16) & 1u;
    u += 0x7fffu + lsb;
    return (ushort)(u >> 16);
}
__device__ __forceinline__ float bf2f(ushort h){
    return __uint_as_float(((unsigned)h) << 16);
}

typedef __bf16 bf16x8 __attribute__((ext_vector_type(8)));
typedef float  f32x4  __attribute__((ext_vector_type(4)));
union BF8 { bf16x8 v; ushort u[8]; int4 i; };

// ============================ res: X = hist @ start_w + start_b ============================
__global__ void k_res(const float* __restrict__ hist, const float* __restrict__ sw,
                      const float* __restrict__ sb, float* __restrict__ res)
{
    int idx = blockIdx.x*256 + threadIdx.x;
    if (idx >= RBN*LDM) return;
    int r = idx / LDM, col = idx - r*LDM;
    int b = r / N_, n = r - b*N_;
    int l = col >> 6, d = col & 63;
    const float* hp = hist + ((size_t)(b*L_ + l)*N_ + n)*3;
    res[idx] = hp[0]*sw[d] + hp[1]*sw[64+d] + hp[2]*sw[128+d] + sb[d];
}

// ============================ generic fp32 GEMM: C = act(A@W + bias [+C]) =================
// AMODE 0: A[r*K+k].  AMODE 1: r=(b*883+n), k=(l*64+d), A addr = ((b*12+l)*883+n)*64+d.
// CMODE 0: C[r*N+c].  CMODE 1: C addr = (b*12+c)*883+n.
// CMODE 2: bf16 transposed spa_back write: ushort at (b*12+(c>>6))*56512 + n*64 + (c&63).
// OUTBF (CMODE 0 only): store bf16 (ushort) at [r*N+c].
template<int AMODE, int CMODE, bool RELU, bool ADDTO, bool OUTBF=false>
__launch_bounds__(256)
__global__ void gemm_k(const float* __restrict__ A, const float* __restrict__ W,
                       const float* __restrict__ bias, float* __restrict__ C,
                       int M, int N, int K)
{
    __shared__ float As[16][64];
    __shared__ float Ws[16][64];
    const int t  = threadIdx.x;
    const int ty = t >> 4, tx = t & 15;
    const int row0 = blockIdx.y << 6, col0 = blockIdx.x << 6;
    const int lm = t >> 2, lk = (t & 3) << 2;
    const int wk = t >> 4, wj = (t & 15) << 2;
    float acc[4][4] = {};
    const int ar = row0 + lm;
    const bool avalid = ar < M;
    int ab = 0, an = 0;
    size_t abase = 0;
    if (AMODE == 0) abase = (size_t)ar * K;
    else { ab = ar / N_; an = ar - ab*N_; }

    for (int k0 = 0; k0 < K; k0 += 16) {
        float4 av = make_float4(0.f,0.f,0.f,0.f);
        if (avalid) {
            int k = k0 + lk;
            if (AMODE == 0) av = *(const float4*)(A + abase + k);
            else {
                int l = k >> 6, d = k & 63;
                av = *(const float4*)(A + (((size_t)(ab*L_ + l)*N_ + an) << 6) + d);
            }
        }
        As[lk+0][lm]=av.x; As[lk+1][lm]=av.y; As[lk+2][lm]=av.z; As[lk+3][lm]=av.w;
        {
            int k = k0 + wk, j = col0 + wj;
            float4 wv;
            if (j + 3 < N) wv = *(const float4*)(W + (size_t)k*N + j);
            else {
                wv.x = (j   < N) ? W[(size_t)k*N + j  ] : 0.f;
                wv.y = (j+1 < N) ? W[(size_t)k*N + j+1] : 0.f;
                wv.z = (j+2 < N) ? W[(size_t)k*N + j+2] : 0.f;
                wv.w = 0.f;
            }
            Ws[wk][wj+0]=wv.x; Ws[wk][wj+1]=wv.y; Ws[wk][wj+2]=wv.z; Ws[wk][wj+3]=wv.w;
        }
        __syncthreads();
        #pragma unroll
        for (int kk = 0; kk < 16; ++kk) {
            const float4 a = *(const float4*)&As[kk][ty<<2];
            const float4 b = *(const float4*)&Ws[kk][tx<<2];
            float ar_[4] = {a.x,a.y,a.z,a.w};
            float br_[4] = {b.x,b.y,b.z,b.w};
            #pragma unroll
            for (int i = 0; i < 4; ++i)
                #pragma unroll
                for (int j = 0; j < 4; ++j)
                    acc[i][j] += ar_[i]*br_[j];
        }
        __syncthreads();
    }
    #pragma unroll
    for (int i = 0; i < 4; ++i) {
        int r = row0 + (ty<<2) + i;
        if (r >= M) continue;
        #pragma unroll
        for (int j = 0; j < 4; ++j) {
            int c = col0 + (tx<<2) + j;
            if (c >= N) continue;
            float v = acc[i][j];
            if (bias) v += bias[c];
            if (ADDTO) v += C[(size_t)r*N + c];
            if (RELU)  v = fmaxf(v, 0.f);
            if (CMODE == 2) {
                int b = r / N_, n = r - (r/N_)*N_;
                ((ushort*)C)[((size_t)(b*L_ + (c>>6)))*NDM + (size_t)n*64 + (c&63)] = f2bf(v);
            } else if (OUTBF) {
                ((ushort*)C)[(size_t)r*N + c] = f2bf(v);
            } else if (CMODE == 0) {
                C[(size_t)r*N + c] = v;
            } else {
                int b = r / N_, n = r - (r/N_)*N_;
                C[(size_t)(b*L_ + c)*N_ + n] = v;
            }
        }
    }
}

// ============== MFMA GEMM (direct-from-global): out = [relu](A@W + bias [+res]) ==============
// A: bf16 [M][K] row-major. WT: bf16 [N][K] ([col][k]). CT col-tiles of 16 per block.
// RES: v += resF[r*N+c]; resF written back fp32; outB always bf16 [M][N].
// mfma_f32_16x16x32_bf16 layouts (m89-verified): A[m=lane&15][k=(lane>>4)*8+j],
// B[k=(lane>>4)*8+j][n=lane&15], C/D: col=lane&15, row=(lane>>4)*4+reg.
template<int CT, bool RELU, bool RES>
__launch_bounds__(256)
__global__ void mfma_gemm(const ushort* __restrict__ A, const ushort* __restrict__ WT,
                          const float* __restrict__ bias, float* __restrict__ resF,
                          ushort* __restrict__ outB, int M, int N, int K)
{
    const int t = threadIdx.x, wv = t >> 6, l = t & 63;
    const int lr = l & 15, lk = l >> 4;
    const int row0 = blockIdx.y*64 + wv*16;
    const int col0 = blockIdx.x * (CT*16);
    int arr = row0 + lr; if (arr >= M) arr = M-1;
    const ushort* ap = A + (size_t)arr*K + lk*8;
    f32x4 acc[CT] = {};
    for (int k0 = 0; k0 < K; k0 += 32) {
        BF8 af; af.i = *(const int4*)(ap + k0);
        #pragma unroll
        for (int ct = 0; ct < CT; ++ct) {
            BF8 bf; bf.i = *(const int4*)&WT[(size_t)(col0 + ct*16 + lr)*K + k0 + lk*8];
            acc[ct] = __builtin_amdgcn_mfma_f32_16x16x32_bf16(af.v, bf.v, acc[ct], 0, 0, 0);
        }
    }
    #pragma unroll
    for (int ct = 0; ct < CT; ++ct) {
        int c = col0 + ct*16 + lr;
        float bv = bias ? bias[c] : 0.f;
        #pragma unroll
        for (int g = 0; g < 4; ++g) {
            int r = row0 + lk*4 + g;
            if (r >= M) continue;
            float v = acc[ct][g] + bv;
            if (RELU) v = fmaxf(v, 0.f);
            if (RES) {
                v += resF[(size_t)r*N + c];
                resF[(size_t)r*N + c] = v;
            }
            outB[(size_t)r*N + c] = f2bf(v);
        }
    }
}

// ============== temp_in via split-K MFMA: out[384][128] += AT[384][56512] @ WtT^T ==============
#define TCH 1024
__launch_bounds__(256)
__global__ void temp_in_mfma(const ushort* __restrict__ AT, const ushort* __restrict__ WtT,
                             float* __restrict__ out)
{
    const int t = threadIdx.x, wv = t >> 6, l = t & 63;
    const int lr = l & 15, lk = l >> 4;
    const int row0 = blockIdx.y * 96;
    const int c0 = wv * 32;
    const int k0b = blockIdx.x * TCH;
    const int kend = (k0b + TCH < NDM) ? (k0b + TCH) : NDM;
    f32x4 acc[6][2] = {};
    for (int k0 = k0b; k0 < kend; k0 += 32) {
        BF8 b0, b1;
        b0.i = *(const int4*)&WtT[(size_t)(c0 + lr)*NDM + k0 + lk*8];
        b1.i = *(const int4*)&WtT[(size_t)(c0 + 16 + lr)*NDM + k0 + lk*8];
        #pragma unroll
        for (int m = 0; m < 6; ++m) {
            BF8 af; af.i = *(const int4*)&AT[(size_t)(row0 + m*16 + lr)*NDM + k0 + lk*8];
            acc[m][0] = __builtin_amdgcn_mfma_f32_16x16x32_bf16(af.v, b0.v, acc[m][0], 0, 0, 0);
            acc[m][1] = __builtin_amdgcn_mfma_f32_16x16x32_bf16(af.v, b1.v, acc[m][1], 0, 0, 0);
        }
    }
    #pragma unroll
    for (int m = 0; m < 6; ++m)
        #pragma unroll
        for (int ct = 0; ct < 2; ++ct) {
            int c = c0 + ct*16 + lr;
            #pragma unroll
            for (int g = 0; g < 4; ++g) {
                int r = row0 + m*16 + lk*4 + g;
                atomicAdd(&out[(size_t)r*128 + c], acc[m][ct][g]);
            }
        }
}

// ============================ attention scores sc_s / sc_d ============================
__global__ void k_sc(const float* __restrict__ h, const float* __restrict__ as_,
                     const float* __restrict__ ad_, float* __restrict__ scs,
                     float* __restrict__ scd, int R)
{
    int r = blockIdx.x*256 + threadIdx.x;
    if (r >= R) return;
    const float* hr = h + (size_t)r*128;
    #pragma unroll
    for (int hh = 0; hh < 4; ++hh) {
        float ss = 0.f, sd = 0.f;
        #pragma unroll
        for (int k = 0; k < 32; ++k) {
            float hv = hr[hh*32 + k];
            ss += hv*as_[hh*32+k];
            sd += hv*ad_[hh*32+k];
        }
        scs[(size_t)r*4+hh] = ss;
        scd[(size_t)r*4+hh] = sd;
    }
}

// ============================ edge softmax ============================
__device__ __forceinline__ unsigned enc_f(float x){
    unsigned u = __float_as_uint(x);
    return (u & 0x80000000u) ? ~u : (u | 0x80000000u);
}
__device__ __forceinline__ float dec_f(unsigned u){
    return (u & 0x80000000u) ? __uint_as_float(u & 0x7fffffffu) : __uint_as_float(~u);
}
__global__ void k_att1(const float* __restrict__ scs, const float* __restrict__ scd,
                       const int* __restrict__ ei, int E, int NN,
                       float* __restrict__ a_buf, unsigned* __restrict__ nmax)
{
    int idx = blockIdx.x*256 + threadIdx.x;
    if (idx >= B_*E) return;
    int b = idx / E, e = idx - b*E;
    int s = ei[e], tg = ei[E+e];
    const float* ps = scs + (size_t)(b*NN+s)*4;
    const float* pd = scd + (size_t)(b*NN+tg)*4;
    unsigned* pm = nmax + (size_t)(b*NN+tg)*4;
    float* pa = a_buf + (size_t)idx*4;
    #pragma unroll
    for (int hh = 0; hh < 4; ++hh) {
        float al = ps[hh] + pd[hh];
        al = al > 0.f ? al : 0.2f*al;
        pa[hh] = al;
        atomicMax(pm + hh, enc_f(al));
    }
}
__global__ void k_att2(const int* __restrict__ ei, int E, int NN,
                       float* __restrict__ a_buf, const unsigned* __restrict__ nmax,
                       float* __restrict__ nsum)
{
    int idx = blockIdx.x*256 + threadIdx.x;
    if (idx >= B_*E) return;
    int b = idx / E, e = idx - b*E;
    int tg = ei[E+e];
    const unsigned* pm = nmax + (size_t)(b*NN+tg)*4;
    float* ns = nsum + (size_t)(b*NN+tg)*4;
    float* pa = a_buf + (size_t)idx*4;
    #pragma unroll
    for (int hh = 0; hh < 4; ++hh) {
        float ex = expf(pa[hh] - dec_f(pm[hh]));
        pa[hh] = ex;
        atomicAdd(ns + hh, ex);
    }
}

// ============================ CSR build (target-indexed) ============================
__global__ void k_count(const int* __restrict__ ei, int E, int* __restrict__ counts){
    int e = blockIdx.x*256 + threadIdx.x;
    if (e < E) atomicAdd(&counts[ei[E + e]], 1);
}
__global__ void k_scan(const int* __restrict__ counts, int* __restrict__ off,
                       int* __restrict__ cur, int n)
{
    __shared__ int s[1024];
    int t = threadIdx.x;
    int v0 = (t < n) ? counts[t] : 0;
    s[t] = v0;
    __syncthreads();
    for (int o = 1; o < 1024; o <<= 1) {
        int v = (t >= o) ? s[t-o] : 0;
        __syncthreads();
        s[t] += v;
        __syncthreads();
    }
    if (t < n) {
        off[t+1] = s[t];
        cur[t] = s[t] - v0;
        if (t == 0) off[0] = 0;
    }
}
__global__ void k_fill(const int* __restrict__ ei, int E, int* __restrict__ cur,
                       int* __restrict__ lst){
    int e = blockIdx.x*256 + threadIdx.x;
    if (e < E) {
        int pos = atomicAdd(&cur[ei[E+e]], 1);
        lst[pos] = e;
    }
}

// ============================ GAT aggregation (CSR gather) ============================
template<bool USE_ATT, bool OUTBF>
__global__ void k_gather(const float* __restrict__ h, const float* __restrict__ a_buf,
                         const float* __restrict__ nsum, const float* __restrict__ att,
                         const int* __restrict__ ei, const int* __restrict__ off,
                         const int* __restrict__ lst, const float* __restrict__ bias,
                         float* __restrict__ out, int E, int NN)
{
    int bn = blockIdx.x;
    int b = bn / NN, n = bn - b*NN;
    int c = threadIdx.x;
    int hh = c >> 5;
    float rn = 1.f / nsum[(size_t)bn*4 + hh];
    int o0 = off[n], o1 = off[n+1];
    float acc = 0.f;
    for (int i = o0; i < o1; ++i) {
        int e = lst[i];
        float a = a_buf[((size_t)b*E + e)*4 + hh] * rn;
        if (USE_ATT) a *= att[(size_t)b*E + e];
        int s = ei[e];
        acc += a * h[((size_t)b*NN + s)*128 + c];
    }
    if (OUTBF) ((ushort*)out)[(size_t)bn*128 + c] = f2bf(acc + bias[c]);
    else       out[(size_t)bn*128 + c] = acc + bias[c];
}

// ============================ weight prep: bf16 transposes ============================
__global__ void k_prepW2(const float* __restrict__ W2, ushort* __restrict__ W2T)
{
    int idx = blockIdx.x*256 + threadIdx.x;   // 512*128
    if (idx >= 512*128) return;
    int k = idx >> 7, c = idx & 127;
    W2T[(size_t)c*512 + k] = f2bf(W2[idx]);
}
// generic W[K][N] -> WT[N][K] bf16
__global__ void k_prepT(const float* __restrict__ W, ushort* __restrict__ WT, int K, int N)
{
    int idx = blockIdx.x*256 + threadIdx.x;
    if (idx >= K*N) return;
    int k = idx / N, c = idx - k*N;
    WT[(size_t)c*K + k] = f2bf(W[idx]);
}
// tr_temp_w [56512][128] -> WtT [128][56512] bf16 (tiled)
__global__ void k_prepWtT(const float* __restrict__ W, ushort* __restrict__ WT)
{
    __shared__ ushort tile[128][129];
    int k0 = blockIdx.x * 128;
    int t = threadIdx.x;
    for (int i = t; i < 128*128; i += 256) {
        int k = i >> 7, c = i & 127;
        int kk = k0 + k;
        tile[c][k] = (kk < NDM) ? f2bf(W[(size_t)kk*128 + c]) : (ushort)0;
    }
    __syncthreads();
    for (int i = t; i < 128*128; i += 256) {
        int c = i >> 7, k = i & 127;
        int kk = k0 + k;
        if (kk < NDM) WT[(size_t)c*NDM + kk] = tile[c][k];
    }
}

// ======== MFMA fused extractor stage2: att = sigmoid(relu(relu(P[es]+Q[et])@W2+b2)@w3+b3) ===
__launch_bounds__(256)
__global__ void ext2_mfma(const ushort* __restrict__ P, const ushort* __restrict__ Q,
                          const ushort* __restrict__ W2T, const float* __restrict__ b2,
                          const float* __restrict__ w3, const float* __restrict__ b3p,
                          const int* __restrict__ ei, float* __restrict__ att,
                          int E, int NN)
{
    __shared__ ushort Bs[128*72];          // [col][k], col stride 72 (144B, 16B-aligned)
    const int t  = threadIdx.x;
    const int wv = t >> 6, l = t & 63;
    const int row0 = blockIdx.x*64 + wv*16;
    const int lr = l & 15, lk = l >> 4;

    int r = row0 + lr;
    int b = r / E, e = r - b*E;
    const ushort* pr = P + ((size_t)b*NN + ei[e])*512 + lk*8;
    const ushort* qr = Q + ((size_t)b*NN + ei[E+e])*512 + lk*8;

    f32x4 acc[8] = {};
    for (int kc = 0; kc < 16; ++kc) {
        __syncthreads();
        #pragma unroll
        for (int i = 0; i < 2; ++i) {
            int it = t + i*256;            // [0,512)
            int c = it >> 2, part = it & 3;
            *(int4*)&Bs[c*72 + part*8] = *(const int4*)&W2T[(size_t)c*512 + kc*32 + part*8];
        }
        BF8 af;
        BF8 pu, qu;
        pu.i = *(const int4*)(pr + kc*32);
        qu.i = *(const int4*)(qr + kc*32);
        #pragma unroll
        for (int j = 0; j < 8; ++j)
            af.u[j] = f2bf(fmaxf(bf2f(pu.u[j]) + bf2f(qu.u[j]), 0.f));
        __syncthreads();
        #pragma unroll
        for (int ct = 0; ct < 8; ++ct) {
            BF8 bfm;
            bfm.v = *(const bf16x8*)&Bs[(ct*16 + lr)*72 + lk*8];
            acc[ct] = __builtin_amdgcn_mfma_f32_16x16x32_bf16(af.v, bfm.v, acc[ct], 0, 0, 0);
        }
    }
    float part[4] = {0.f,0.f,0.f,0.f};
    #pragma unroll
    for (int ct = 0; ct < 8; ++ct) {
        int c = ct*16 + lr;
        float b2v = b2[c], w3v = w3[c];
        #pragma unroll
        for (int g = 0; g < 4; ++g)
            part[g] += fmaxf(acc[ct][g] + b2v, 0.f) * w3v;
    }
    #pragma unroll
    for (int m = 1; m < 16; m <<= 1)
        #pragma unroll
        for (int g = 0; g < 4; ++g)
            part[g] += __shfl_xor(part[g], m, 64);
    if (lr == 0) {
        float b3 = b3p[0];
        #pragma unroll
        for (int g = 0; g < 4; ++g) {
            int rr = row0 + lk*4 + g;
            att[rr] = 1.f/(1.f + expf(-(part[g] + b3)));
        }
    }
}

// ============================ misc ============================
__global__ void k_bias_fill(float* __restrict__ dst, const float* __restrict__ bias, int n){
    int i = blockIdx.x*256 + threadIdx.x;
    if (i < n) dst[i] = bias[i & 127];
}

// ============================ hid concat (fp32 + bf16 shadow) ============================
__global__ void k_hid(const float* __restrict__ ts_res, const float* __restrict__ ts_temp,
                      const float* __restrict__ node_emb, const float* __restrict__ tid_emb,
                      const float* __restrict__ diw_emb, const float* __restrict__ hist,
                      float* __restrict__ hid, ushort* __restrict__ hidB)
{
    int idx = blockIdx.x*256 + threadIdx.x;
    if (idx >= RBN*320) return;
    int r = idx / 320, c = idx - r*320;
    int b = r / N_, n = r - b*N_;
    float v;
    if (c < 64)        v = ts_res[(size_t)r*64 + c];
    else if (c < 128)  v = ts_temp[(size_t)r*64 + (c-64)];
    else if (c < 192)  v = node_emb[(size_t)n*64 + (c-128)];
    else if (c < 256) {
        int tid = (int)hist[((size_t)(b*L_ + (L_-1))*N_ + n)*3 + 1];
        v = tid_emb[(size_t)tid*64 + (c-192)];
    } else {
        int diw = (int)hist[((size_t)(b*L_ + (L_-1))*N_ + n)*3 + 2];
        v = diw_emb[(size_t)diw*64 + (c-256)];
    }
    hid[idx] = v;
    hidB[idx] = f2bf(v);
}

// =====================================================================================
extern "C" void kernel_launch(void* const* d_in, const int* in_sizes, int n_in,
                              void* d_out, int out_size, void* d_ws, size_t ws_size,
                              hipStream_t stream)
{
    (void)in_sizes; (void)n_in; (void)out_size; (void)ws_size;
    const float* hist      = (const float*)d_in[0];
    const int*   ei_sp     = (const int*)  d_in[1];
    const int*   ei_tp     = (const int*)  d_in[2];
    const float* node_emb  = (const float*)d_in[3];
    const float* tid_emb   = (const float*)d_in[4];
    const float* diw_emb   = (const float*)d_in[5];
    const float* start_w   = (const float*)d_in[6];
    const float* start_b   = (const float*)d_in[7];
    const float* ts_w      = (const float*)d_in[8];
    const float* ts_b      = (const float*)d_in[9];
    const float* tr_spat_w = (const float*)d_in[10];
    const float* tr_spat_b = (const float*)d_in[11];
    const float* inv_spat_w= (const float*)d_in[12];
    const float* inv_spat_b= (const float*)d_in[13];
    const float* tr_temp_w = (const float*)d_in[14];
    const float* tr_temp_b = (const float*)d_in[15];
    const float* inv_temp_w= (const float*)d_in[16];
    const float* inv_temp_b= (const float*)d_in[17];
    const float* gat_sp_w  = (const float*)d_in[18];
    const float* gat_sp_as = (const float*)d_in[19];
    const float* gat_sp_ad = (const float*)d_in[20];
    const float* gat_sp_b  = (const float*)d_in[21];
    const float* ext_sp_w1 = (const float*)d_in[22];
    const float* ext_sp_b1 = (const float*)d_in[23];
    const float* ext_sp_w2 = (const float*)d_in[24];
    const float* ext_sp_b2 = (const float*)d_in[25];
    const float* ext_sp_w3 = (const float*)d_in[26];
    const float* ext_sp_b3 = (const float*)d_in[27];
    const float* gat_tp_w  = (const float*)d_in[28];
    const float* gat_tp_as = (const float*)d_in[29];
    const float* gat_tp_ad = (const float*)d_in[30];
    const float* gat_tp_b  = (const float*)d_in[31];
    const float* ext_tp_w1 = (const float*)d_in[32];
    const float* ext_tp_b1 = (const float*)d_in[33];
    const float* ext_tp_w2 = (const float*)d_in[34];
    const float* ext_tp_b2 = (const float*)d_in[35];
    const float* ext_tp_w3 = (const float*)d_in[36];
    const float* ext_tp_b3 = (const float*)d_in[37];
    const float* enc_w1    = (const float*)d_in[38];
    const float* enc_b1    = (const float*)d_in[39];
    const float* enc_w2    = (const float*)d_in[40];
    const float* enc_b2    = (const float*)d_in[41];
    const float* reg_w     = (const float*)d_in[42];
    const float* reg_b     = (const float*)d_in[43];
    float* out = (float*)d_out;

    // ---------------- workspace layout ----------------
    size_t o = 0;
    char* wsb = (char*)d_ws;
    auto alloc = [&](size_t nfloats) -> float* {
        float* p = (float*)(wsb + o);
        o += ((nfloats + 63) & ~(size_t)63) * 4;
        return p;
    };
    float* R0      = alloc((size_t)RBN*LDM);   // res -> P_sp(bf16) -> AT(bf16) -> temp_back -> hidF
    float* R1      = alloc((size_t)RBN*512);   // Q_sp(bf16) -> hidB+R1b
    float* ts_res  = alloc((size_t)RBN*64);
    float* spaX    = alloc((size_t)RBN*128);
    float* h_sp    = alloc((size_t)RBN*128);
    float* sc_s    = alloc((size_t)RBN*4);
    float* sc_d    = alloc((size_t)RBN*4);
    unsigned* nmax = (unsigned*)alloc((size_t)RBN*4);
    float* nsum    = alloc((size_t)RBN*4);
    float* a_buf   = alloc((size_t)B_*E_SP*4);
    float* att     = alloc((size_t)B_*E_SP);
    float* emb     = alloc((size_t)RBN*128);   // bf16 embB region
    int*   csr     = (int*)alloc(17024);
    float* temp_in = alloc((size_t)RBL*128);
    float* h_tp    = alloc((size_t)RBL*128);
    float* tout_t  = alloc((size_t)RBL*128);
    float* P_t     = alloc((size_t)RBL*512);   // bf16 (half used)
    float* Q_t     = alloc((size_t)RBL*512);   // bf16 (half used)
    float* ts_temp = alloc((size_t)RBN*64);
    ushort* W2T_sp = (ushort*)alloc(32768);    // 128x512 bf16
    ushort* W2T_tp = (ushort*)alloc(32768);
    ushort* WtT    = (ushort*)alloc((size_t)NDM*64);   // 128x56512 bf16 (7.23M ushort)
    ushort* w1T_enc= (ushort*)alloc(3*320*160);        // 3x [320][320] bf16
    ushort* w2T_enc= (ushort*)alloc(3*320*160);
    ushort* w1aT_sp= (ushort*)alloc(512*64);           // [512][128] bf16
    ushort* w1bT_sp= (ushort*)alloc(512*64);
    ushort* w1aT_tp= (ushort*)alloc(512*64);
    ushort* w1bT_tp= (ushort*)alloc(512*64);

    ushort* embB = (ushort*)emb;
    ushort* hidB = (ushort*)R1;
    ushort* R1b  = (ushort*)(R1 + 5000000);    // 20MB offset inside 57.9MB region
    ushort* AT   = (ushort*)R0;                // spa_back bf16 transposed [384][56512]

    int* counts_sp = csr;
    int* off_sp    = csr + 883;
    int* cur_sp    = csr + 1767;
    int* list_sp   = csr + 2650;
    int* counts_tp = csr + 16778;
    int* off_tp    = csr + 16790;
    int* cur_tp    = csr + 16803;
    int* list_tp   = csr + 16815;

    // ---------------- CSR builds + weight prep ----------------
    hipMemsetAsync(counts_sp, 0, 883*4, stream);
    k_count<<<cdiv_h(E_SP,256),256,0,stream>>>(ei_sp, E_SP, counts_sp);
    k_scan<<<1,1024,0,stream>>>(counts_sp, off_sp, cur_sp, 883);
    k_fill<<<cdiv_h(E_SP,256),256,0,stream>>>(ei_sp, E_SP, cur_sp, list_sp);
    hipMemsetAsync(counts_tp, 0, 12*4, stream);
    k_count<<<1,256,0,stream>>>(ei_tp, E_TP, counts_tp);
    k_scan<<<1,1024,0,stream>>>(counts_tp, off_tp, cur_tp, 12);
    k_fill<<<1,256,0,stream>>>(ei_tp, E_TP, cur_tp, list_tp);
    k_prepW2<<<cdiv_h(512*128,256),256,0,stream>>>(ext_sp_w2, W2T_sp);
    k_prepW2<<<cdiv_h(512*128,256),256,0,stream>>>(ext_tp_w2, W2T_tp);
    k_prepWtT<<<cdiv_h(NDM,128),256,0,stream>>>(tr_temp_w, WtT);
    for (int i = 0; i < 3; ++i) {
        k_prepT<<<cdiv_h(320*320,256),256,0,stream>>>(enc_w1 + (size_t)i*320*320, w1T_enc + (size_t)i*320*320, 320, 320);
        k_prepT<<<cdiv_h(320*320,256),256,0,stream>>>(enc_w2 + (size_t)i*320*320, w2T_enc + (size_t)i*320*320, 320, 320);
    }
    k_prepT<<<cdiv_h(128*512,256),256,0,stream>>>(ext_sp_w1,           w1aT_sp, 128, 512);
    k_prepT<<<cdiv_h(128*512,256),256,0,stream>>>(ext_sp_w1 + 128*512, w1bT_sp, 128, 512);
    k_prepT<<<cdiv_h(128*512,256),256,0,stream>>>(ext_tp_w1,           w1aT_tp, 128, 512);
    k_prepT<<<cdiv_h(128*512,256),256,0,stream>>>(ext_tp_w1 + 128*512, w1bT_tp, 128, 512);

    // ---------------- res / ts_res / spa_in ----------------
    k_res<<<cdiv_h(RBN*LDM,256),256,0,stream>>>(hist, start_w, start_b, R0);
    gemm_k<0,0,false,false><<<dim3(1,442),256,0,stream>>>(R0, ts_w, ts_b, ts_res, RBN, 64, LDM);
    gemm_k<0,0,false,false><<<dim3(2,442),256,0,stream>>>(R0, tr_spat_w, tr_spat_b, spaX, RBN, 128, LDM);

    // ---------------- spatial GAT ----------------
    gemm_k<0,0,false,false><<<dim3(2,442),256,0,stream>>>(spaX, gat_sp_w, nullptr, h_sp, RBN, 128, 128);
    k_sc<<<cdiv_h(RBN,256),256,0,stream>>>(h_sp, gat_sp_as, gat_sp_ad, sc_s, sc_d, RBN);
    hipMemsetAsync(nmax, 0, (size_t)RBN*4*4, stream);
    hipMemsetAsync(nsum, 0, (size_t)RBN*4*4, stream);
    k_att1<<<cdiv_h(B_*E_SP,256),256,0,stream>>>(sc_s, sc_d, ei_sp, E_SP, N_, a_buf, nmax);
    k_att2<<<cdiv_h(B_*E_SP,256),256,0,stream>>>(ei_sp, E_SP, N_, a_buf, nmax, nsum);
    k_gather<false,true><<<RBN,128,0,stream>>>(h_sp, a_buf, nsum, nullptr, ei_sp, off_sp, list_sp,
                                               gat_sp_b, emb, E_SP, N_);
    // extractor: P = emb@W1a + b1 (bf16); Q = emb@W1b (bf16); att = sigmoid(MLP) via MFMA
    mfma_gemm<8,false,false><<<dim3(4,442),256,0,stream>>>(embB, w1aT_sp, ext_sp_b1, nullptr,
                                                           (ushort*)R0, RBN, 512, 128);
    mfma_gemm<8,false,false><<<dim3(4,442),256,0,stream>>>(embB, w1bT_sp, nullptr, nullptr,
                                                           (ushort*)R1, RBN, 512, 128);
    ext2_mfma<<<(B_*E_SP)/64,256,0,stream>>>((const ushort*)R0, (const ushort*)R1, W2T_sp,
                                             ext_sp_b2, ext_sp_w3, ext_sp_b3, ei_sp, att, E_SP, N_);
    k_gather<true,false><<<RBN,128,0,stream>>>(h_sp, a_buf, nsum, att, ei_sp, off_sp, list_sp,
                                               gat_sp_b, spaX, E_SP, N_);

    // ---------------- back-projection (bf16 transposed) + temporal input (MFMA split-K) ----
    gemm_k<0,2,false,false><<<dim3(12,442),256,0,stream>>>(spaX, inv_spat_w, inv_spat_b, R0, RBN, LDM, 128);
    k_bias_fill<<<cdiv_h(RBL*128,256),256,0,stream>>>(temp_in, tr_temp_b, RBL*128);
    temp_in_mfma<<<dim3(56,4),256,0,stream>>>(AT, WtT, temp_in);

    // ---------------- temporal GAT ----------------
    gemm_k<0,0,false,false><<<dim3(2,6),256,0,stream>>>(temp_in, gat_tp_w, nullptr, h_tp, RBL, 128, 128);
    k_sc<<<cdiv_h(RBL,256),256,0,stream>>>(h_tp, gat_tp_as, gat_tp_ad, sc_s, sc_d, RBL);
    hipMemsetAsync(nmax, 0, (size_t)RBL*4*4, stream);
    hipMemsetAsync(nsum, 0, (size_t)RBL*4*4, stream);
    k_att1<<<cdiv_h(B_*E_TP,256),256,0,stream>>>(sc_s, sc_d, ei_tp, E_TP, NT_, a_buf, nmax);
    k_att2<<<cdiv_h(B_*E_TP,256),256,0,stream>>>(ei_tp, E_TP, NT_, a_buf, nmax, nsum);
    k_gather<false,true><<<RBL,128,0,stream>>>(h_tp, a_buf, nsum, nullptr, ei_tp, off_tp, list_tp,
                                               gat_tp_b, emb, E_TP, NT_);
    mfma_gemm<8,false,false><<<dim3(4,6),256,0,stream>>>(embB, w1aT_tp, ext_tp_b1, nullptr,
                                                         (ushort*)P_t, RBL, 512, 128);
    mfma_gemm<8,false,false><<<dim3(4,6),256,0,stream>>>(embB, w1bT_tp, nullptr, nullptr,
                                                         (ushort*)Q_t, RBL, 512, 128);
    ext2_mfma<<<(B_*E_TP)/64,256,0,stream>>>((const ushort*)P_t, (const ushort*)Q_t, W2T_tp,
                                             ext_tp_b2, ext_tp_w3, ext_tp_b3, ei_tp, att, E_TP, NT_);
    k_gather<true,false><<<RBL,128,0,stream>>>(h_tp, a_buf, nsum, att, ei_tp, off_tp, list_tp,
                                               gat_tp_b, tout_t, E_TP, NT_);

    // ---------------- temporal back-projection + ts_temp ----------------
    gemm_k<0,0,false,false><<<dim3(883,6),256,0,stream>>>(tout_t, inv_temp_w, inv_temp_b, R0, RBL, NDM, 128);
    gemm_k<1,0,false,false><<<dim3(1,442),256,0,stream>>>(R0, ts_w, ts_b, ts_temp, RBN, 64, LDM);

    // ---------------- concat + residual MLP encoder (MFMA) + regression head ----------------
    k_hid<<<cdiv_h(RBN*320,256),256,0,stream>>>(ts_res, ts_temp, node_emb, tid_emb, diw_emb, hist,
                                                R0, hidB);
    for (int i = 0; i < 3; ++i) {
        mfma_gemm<10,true,false><<<dim3(2,442),256,0,stream>>>(hidB, w1T_enc + (size_t)i*320*320,
                                                               enc_b1 + i*320, nullptr, R1b, RBN, 320, 320);
        mfma_gemm<10,false,true><<<dim3(2,442),256,0,stream>>>(R1b, w2T_enc + (size_t)i*320*320,
                                                               enc_b2 + i*320, R0, hidB, RBN, 320, 320);
    }
    gemm_k<0,1,false,false><<<dim3(1,442),256,0,stream>>>(R0, reg_w, reg_b, out, RBN, 12, 320);
}

// Round 4
// 1693.752 us; speedup vs baseline: 1.6712x; 1.0569x over previous
//
#include <hip/hip_runtime.h>
#include <hip/hip_bf16.h>
#include <cstdint>
#include <cstddef>

#define B_   32
#define L_   12
#define N_   883
#define DM_  64
#define E_SP 14128
#define E_TP 144
#define NT_  12
#define RBN  28256      // B*N
#define RBL  384        // B*L
#define LDM  768        // L*DM
#define NDM  56512      // N*DM

static inline int cdiv_h(int a, int b){ return (a+b-1)/b; }

// bf16 round-to-nearest-even from float
__device__ __forceinline__ ushort f2bf(float f){
    unsigned u = __float_as_uint(f);
    unsigned lsb = (u >> 16) & 1u;
    u += 0x7fffu + lsb;
    return (ushort)(u >> 16);
}
__device__ __forceinline__ float bf2f(ushort h){
    return __uint_as_float(((unsigned)h) << 16);
}

typedef __bf16 bf16x8 __attribute__((ext_vector_type(8)));
typedef float  f32x4  __attribute__((ext_vector_type(4)));
union BF8 { bf16x8 v; ushort u[8]; unsigned w[4]; int4 i; };

// ============================ res: X = hist @ start_w + start_b (hi/lo bf16) ==============
__global__ void k_res(const float* __restrict__ hist, const float* __restrict__ sw,
                      const float* __restrict__ sb, ushort* __restrict__ resHi,
                      ushort* __restrict__ resLo)
{
    int idx = blockIdx.x*256 + threadIdx.x;
    if (idx >= RBN*LDM) return;
    int r = idx / LDM, col = idx - r*LDM;
    int b = r / N_, n = r - b*N_;
    int l = col >> 6, d = col & 63;
    const float* hp = hist + ((size_t)(b*L_ + l)*N_ + n)*3;
    float v = hp[0]*sw[d] + hp[1]*sw[64+d] + hp[2]*sw[128+d] + sb[d];
    ushort hi = f2bf(v);
    resHi[idx] = hi;
    resLo[idx] = f2bf(v - bf2f(hi));
}

// ============== generalized MFMA GEMM (direct-from-global) ==============
// A bf16. AMODE 0: A[r*K+k]. AMODE 1: r=(b*883+n), k=(l*64+d), addr (b*12+l)*56512 + n*64 + d.
// EPI 0: bf16 out[r*N+c]. EPI 1: f32 out[r*N+c]. EPI 2: head scatter f32 out[(b*12+c)*883+n], c<12.
// EPI 3: bf16 AT scatter out[(b*12+(c>>6))*56512 + n*64 + (c&63)].
// RES (EPI 0 only): v += resF[r*N+c], resF written back fp32.
// mfma_f32_16x16x32_bf16 layouts (m89-verified): A[m=lane&15][k=(lane>>4)*8+j],
// B[k=(lane>>4)*8+j][n=lane&15], C/D: col=lane&15, row=(lane>>4)*4+reg.
template<int CT, int AMODE, int EPI, bool RELU, bool RES>
__launch_bounds__(256)
__global__ void mgemm(const ushort* __restrict__ A, const ushort* __restrict__ WT,
                      const float* __restrict__ bias, float* __restrict__ resF,
                      void* __restrict__ outP, int M, int N, int K)
{
    const int t = threadIdx.x, wv = t >> 6, l = t & 63;
    const int lr = l & 15, lk = l >> 4;
    const int row0 = blockIdx.y*64 + wv*16;
    const int col0 = blockIdx.x * (CT*16);
    int arr = row0 + lr; if (arr >= M) arr = M-1;
    int ab = 0, an = 0;
    if (AMODE == 1) { ab = arr / N_; an = arr - ab*N_; }
    const ushort* ap = A + (size_t)arr*K + lk*8;
    f32x4 acc[CT] = {};
    for (int k0 = 0; k0 < K; k0 += 32) {
        BF8 af;
        if (AMODE == 0) af.i = *(const int4*)(ap + k0);
        else {
            int k = k0 + lk*8; int ll = k >> 6, d = k & 63;
            af.i = *(const int4*)(A + ((size_t)(ab*L_ + ll))*NDM + (size_t)an*64 + d);
        }
        #pragma unroll
        for (int ct = 0; ct < CT; ++ct) {
            BF8 bf; bf.i = *(const int4*)&WT[(size_t)(col0 + ct*16 + lr)*K + k0 + lk*8];
            acc[ct] = __builtin_amdgcn_mfma_f32_16x16x32_bf16(af.v, bf.v, acc[ct], 0, 0, 0);
        }
    }
    #pragma unroll
    for (int ct = 0; ct < CT; ++ct) {
        int c = col0 + ct*16 + lr;
        float bv = 0.f;
        if (EPI == 2) { if (bias && c < 12) bv = bias[c]; }
        else if (bias) bv = bias[c];
        #pragma unroll
        for (int g = 0; g < 4; ++g) {
            int r = row0 + lk*4 + g;
            if (r >= M) continue;
            float v = acc[ct][g] + bv;
            if (RELU) v = fmaxf(v, 0.f);
            if (RES) {
                v += resF[(size_t)r*N + c];
                resF[(size_t)r*N + c] = v;
            }
            if (EPI == 0) {
                ((ushort*)outP)[(size_t)r*N + c] = f2bf(v);
            } else if (EPI == 1) {
                ((float*)outP)[(size_t)r*N + c] = v;
            } else if (EPI == 2) {
                if (c < 12) {
                    int b = r / N_, n = r - (r/N_)*N_;
                    ((float*)outP)[((size_t)(b*L_ + c))*N_ + n] = v;
                }
            } else {
                int b = r / N_, n = r - (r/N_)*N_;
                ((ushort*)outP)[((size_t)(b*L_ + (c>>6)))*NDM + (size_t)n*64 + (c&63)] = f2bf(v);
            }
        }
    }
}

// ============== hi/lo split MFMA GEMM (near-fp32 precision), fp32 out ==============
template<int CT>
__launch_bounds__(256)
__global__ void mgemm_hl(const ushort* __restrict__ Ahi, const ushort* __restrict__ Alo,
                         const ushort* __restrict__ WThi, const ushort* __restrict__ WTlo,
                         const float* __restrict__ bias, float* __restrict__ outF,
                         int M, int N, int K)
{
    const int t = threadIdx.x, wv = t >> 6, l = t & 63;
    const int lr = l & 15, lk = l >> 4;
    const int row0 = blockIdx.y*64 + wv*16;
    const int col0 = blockIdx.x * (CT*16);
    int arr = row0 + lr; if (arr >= M) arr = M-1;
    const ushort* aph = Ahi + (size_t)arr*K + lk*8;
    const ushort* apl = Alo + (size_t)arr*K + lk*8;
    f32x4 acc[CT] = {};
    for (int k0 = 0; k0 < K; k0 += 32) {
        BF8 ah, al_;
        ah.i  = *(const int4*)(aph + k0);
        al_.i = *(const int4*)(apl + k0);
        #pragma unroll
        for (int ct = 0; ct < CT; ++ct) {
            size_t wo = (size_t)(col0 + ct*16 + lr)*K + k0 + lk*8;
            BF8 bh, bl;
            bh.i = *(const int4*)&WThi[wo];
            bl.i = *(const int4*)&WTlo[wo];
            acc[ct] = __builtin_amdgcn_mfma_f32_16x16x32_bf16(ah.v,  bh.v, acc[ct], 0, 0, 0);
            acc[ct] = __builtin_amdgcn_mfma_f32_16x16x32_bf16(al_.v, bh.v, acc[ct], 0, 0, 0);
            acc[ct] = __builtin_amdgcn_mfma_f32_16x16x32_bf16(ah.v,  bl.v, acc[ct], 0, 0, 0);
        }
    }
    #pragma unroll
    for (int ct = 0; ct < CT; ++ct) {
        int c = col0 + ct*16 + lr;
        float bv = bias ? bias[c] : 0.f;
        #pragma unroll
        for (int g = 0; g < 4; ++g) {
            int r = row0 + lk*4 + g;
            if (r >= M) continue;
            outF[(size_t)r*N + c] = acc[ct][g] + bv;
        }
    }
}

// ============== temp_in via split-K MFMA: out[384][128] += AT @ WtT^T ==============
#define TCH 1024
__launch_bounds__(256)
__global__ void temp_in_mfma(const ushort* __restrict__ AT, const ushort* __restrict__ WtT,
                             float* __restrict__ out)
{
    const int t = threadIdx.x, wv = t >> 6, l = t & 63;
    const int lr = l & 15, lk = l >> 4;
    const int row0 = blockIdx.y * 96;
    const int c0 = wv * 32;
    const int k0b = blockIdx.x * TCH;
    const int kend = (k0b + TCH < NDM) ? (k0b + TCH) : NDM;
    f32x4 acc[6][2] = {};
    for (int k0 = k0b; k0 < kend; k0 += 32) {
        BF8 b0, b1;
        b0.i = *(const int4*)&WtT[(size_t)(c0 + lr)*NDM + k0 + lk*8];
        b1.i = *(const int4*)&WtT[(size_t)(c0 + 16 + lr)*NDM + k0 + lk*8];
        #pragma unroll
        for (int m = 0; m < 6; ++m) {
            BF8 af; af.i = *(const int4*)&AT[(size_t)(row0 + m*16 + lr)*NDM + k0 + lk*8];
            acc[m][0] = __builtin_amdgcn_mfma_f32_16x16x32_bf16(af.v, b0.v, acc[m][0], 0, 0, 0);
            acc[m][1] = __builtin_amdgcn_mfma_f32_16x16x32_bf16(af.v, b1.v, acc[m][1], 0, 0, 0);
        }
    }
    #pragma unroll
    for (int m = 0; m < 6; ++m)
        #pragma unroll
        for (int ct = 0; ct < 2; ++ct) {
            int c = c0 + ct*16 + lr;
            #pragma unroll
            for (int g = 0; g < 4; ++g) {
                int r = row0 + m*16 + lk*4 + g;
                atomicAdd(&out[(size_t)r*128 + c], acc[m][ct][g]);
            }
        }
}

// ============================ attention scores (bf16 h) ============================
__global__ void k_sc(const ushort* __restrict__ h, const float* __restrict__ as_,
                     const float* __restrict__ ad_, float* __restrict__ scs,
                     float* __restrict__ scd, int R)
{
    int r = blockIdx.x*256 + threadIdx.x;
    if (r >= R) return;
    const ushort* hr = h + (size_t)r*128;
    #pragma unroll
    for (int hh = 0; hh < 4; ++hh) {
        float ss = 0.f, sd = 0.f;
        #pragma unroll
        for (int k = 0; k < 32; ++k) {
            float hv = bf2f(hr[hh*32 + k]);
            ss += hv*as_[hh*32+k];
            sd += hv*ad_[hh*32+k];
        }
        scs[(size_t)r*4+hh] = ss;
        scd[(size_t)r*4+hh] = sd;
    }
}

// ============================ edge softmax ============================
__device__ __forceinline__ unsigned enc_f(float x){
    unsigned u = __float_as_uint(x);
    return (u & 0x80000000u) ? ~u : (u | 0x80000000u);
}
__device__ __forceinline__ float dec_f(unsigned u){
    return (u & 0x80000000u) ? __uint_as_float(u & 0x7fffffffu) : __uint_as_float(~u);
}
__global__ void k_att1(const float* __restrict__ scs, const float* __restrict__ scd,
                       const int* __restrict__ ei, int E, int NN,
                       float* __restrict__ a_buf, unsigned* __restrict__ nmax)
{
    int idx = blockIdx.x*256 + threadIdx.x;
    if (idx >= B_*E) return;
    int b = idx / E, e = idx - b*E;
    int s = ei[e], tg = ei[E+e];
    const float* ps = scs + (size_t)(b*NN+s)*4;
    const float* pd = scd + (size_t)(b*NN+tg)*4;
    unsigned* pm = nmax + (size_t)(b*NN+tg)*4;
    float* pa = a_buf + (size_t)idx*4;
    #pragma unroll
    for (int hh = 0; hh < 4; ++hh) {
        float al = ps[hh] + pd[hh];
        al = al > 0.f ? al : 0.2f*al;
        pa[hh] = al;
        atomicMax(pm + hh, enc_f(al));
    }
}
__global__ void k_att2(const int* __restrict__ ei, int E, int NN,
                       float* __restrict__ a_buf, const unsigned* __restrict__ nmax,
                       float* __restrict__ nsum)
{
    int idx = blockIdx.x*256 + threadIdx.x;
    if (idx >= B_*E) return;
    int b = idx / E, e = idx - b*E;
    int tg = ei[E+e];
    const unsigned* pm = nmax + (size_t)(b*NN+tg)*4;
    float* ns = nsum + (size_t)(b*NN+tg)*4;
    float* pa = a_buf + (size_t)idx*4;
    #pragma unroll
    for (int hh = 0; hh < 4; ++hh) {
        float ex = expf(pa[hh] - dec_f(pm[hh]));
        pa[hh] = ex;
        atomicAdd(ns + hh, ex);
    }
}

// ============================ CSR build (target-indexed) ============================
__global__ void k_count(const int* __restrict__ ei, int E, int* __restrict__ counts){
    int e = blockIdx.x*256 + threadIdx.x;
    if (e < E) atomicAdd(&counts[ei[E + e]], 1);
}
__global__ void k_scan(const int* __restrict__ counts, int* __restrict__ off,
                       int* __restrict__ cur, int n)
{
    __shared__ int s[1024];
    int t = threadIdx.x;
    int v0 = (t < n) ? counts[t] : 0;
    s[t] = v0;
    __syncthreads();
    for (int o = 1; o < 1024; o <<= 1) {
        int v = (t >= o) ? s[t-o] : 0;
        __syncthreads();
        s[t] += v;
        __syncthreads();
    }
    if (t < n) {
        off[t+1] = s[t];
        cur[t] = s[t] - v0;
        if (t == 0) off[0] = 0;
    }
}
__global__ void k_fill(const int* __restrict__ ei, int E, int* __restrict__ cur,
                       int* __restrict__ lst){
    int e = blockIdx.x*256 + threadIdx.x;
    if (e < E) {
        int pos = atomicAdd(&cur[ei[E+e]], 1);
        lst[pos] = e;
    }
}

// ============================ GAT aggregation (CSR gather, bf16 h, bf16 out) ============
template<bool USE_ATT>
__global__ void k_gather(const ushort* __restrict__ h, const float* __restrict__ a_buf,
                         const float* __restrict__ nsum, const float* __restrict__ att,
                         const int* __restrict__ ei, const int* __restrict__ off,
                         const int* __restrict__ lst, const float* __restrict__ bias,
                         ushort* __restrict__ out, int E, int NN)
{
    int bn = blockIdx.x;
    int b = bn / NN, n = bn - b*NN;
    int c = threadIdx.x;
    int hh = c >> 5;
    float rn = 1.f / nsum[(size_t)bn*4 + hh];
    int o0 = off[n], o1 = off[n+1];
    float acc = 0.f;
    for (int i = o0; i < o1; ++i) {
        int e = lst[i];
        float a = a_buf[((size_t)b*E + e)*4 + hh] * rn;
        if (USE_ATT) a *= att[(size_t)b*E + e];
        int s = ei[e];
        acc += a * bf2f(h[((size_t)b*NN + s)*128 + c]);
    }
    out[(size_t)bn*128 + c] = f2bf(acc + bias[c]);
}

// ============================ weight prep kernels ============================
__global__ void k_prepW2(const float* __restrict__ W2, ushort* __restrict__ W2T)
{
    int idx = blockIdx.x*256 + threadIdx.x;   // 512*128
    if (idx >= 512*128) return;
    int k = idx >> 7, c = idx & 127;
    W2T[(size_t)c*512 + k] = f2bf(W2[idx]);
}
// generic W[K][N] -> WT[N][K] bf16
__global__ void k_prepT(const float* __restrict__ W, ushort* __restrict__ WT, int K, int N)
{
    int idx = blockIdx.x*256 + threadIdx.x;
    if (idx >= K*N) return;
    int k = idx / N, c = idx - k*N;
    WT[(size_t)c*K + k] = f2bf(W[idx]);
}
// W[K][N] -> hi/lo transposed
__global__ void k_prepT_hl(const float* __restrict__ W, ushort* __restrict__ WThi,
                           ushort* __restrict__ WTlo, int K, int N)
{
    int idx = blockIdx.x*256 + threadIdx.x;
    if (idx >= K*N) return;
    int k = idx / N, c = idx - k*N;
    float v = W[idx];
    ushort hi = f2bf(v);
    WThi[(size_t)c*K + k] = hi;
    WTlo[(size_t)c*K + k] = f2bf(v - bf2f(hi));
}
// tr_temp_w [56512][128] -> WtT [128][56512] bf16 (tiled)
__global__ void k_prepWtT(const float* __restrict__ W, ushort* __restrict__ WT)
{
    __shared__ ushort tile[128][129];
    int k0 = blockIdx.x * 128;
    int t = threadIdx.x;
    for (int i = t; i < 128*128; i += 256) {
        int k = i >> 7, c = i & 127;
        int kk = k0 + k;
        tile[c][k] = (kk < NDM) ? f2bf(W[(size_t)kk*128 + c]) : (ushort)0;
    }
    __syncthreads();
    for (int i = t; i < 128*128; i += 256) {
        int c = i >> 7, k = i & 127;
        int kk = k0 + k;
        if (kk < NDM) WT[(size_t)c*NDM + kk] = tile[c][k];
    }
}
// inv_temp_w [128][56512] -> WT [56512][128] bf16 (tiled, 64 cols/block)
__global__ void k_prepT_big(const float* __restrict__ W, ushort* __restrict__ WT)
{
    __shared__ float tile[128][65];
    int c0 = blockIdx.x * 64;
    int t = threadIdx.x;
    for (int i = t; i < 128*64; i += 256) {
        int k = i >> 6, ci = i & 63;
        tile[k][ci] = W[(size_t)k*NDM + c0 + ci];
    }
    __syncthreads();
    for (int i = t; i < 64*128; i += 256) {
        int ci = i >> 7, k = i & 127;
        WT[(size_t)(c0 + ci)*128 + k] = f2bf(tile[k][ci]);
    }
}

// ======== MFMA fused extractor stage2: att = sigmoid(relu(relu(P[es]+Q[et])@W2+b2)@w3+b3) ===
__launch_bounds__(256)
__global__ void ext2_mfma(const ushort* __restrict__ P, const ushort* __restrict__ Q,
                          const ushort* __restrict__ W2T, const float* __restrict__ b2,
                          const float* __restrict__ w3, const float* __restrict__ b3p,
                          const int* __restrict__ ei, float* __restrict__ att,
                          int E, int NN)
{
    __shared__ ushort Bs[128*72];          // [col][k], col stride 72 (144B, 16B-aligned)
    const int t  = threadIdx.x;
    const int wv = t >> 6, l = t & 63;
    const int row0 = blockIdx.x*64 + wv*16;
    const int lr = l & 15, lk = l >> 4;

    int r = row0 + lr;
    int b = r / E, e = r - b*E;
    const ushort* pr = P + ((size_t)b*NN + ei[e])*512 + lk*8;
    const ushort* qr = Q + ((size_t)b*NN + ei[E+e])*512 + lk*8;

    f32x4 acc[8] = {};
    for (int kc = 0; kc < 16; ++kc) {
        __syncthreads();
        #pragma unroll
        for (int i = 0; i < 2; ++i) {
            int it = t + i*256;            // [0,512)
            int c = it >> 2, part = it & 3;
            *(int4*)&Bs[c*72 + part*8] = *(const int4*)&W2T[(size_t)c*512 + kc*32 + part*8];
        }
        BF8 af, pu, qu;
        pu.i = *(const int4*)(pr + kc*32);
        qu.i = *(const int4*)(qr + kc*32);
        // packed bit-trick unpack + add + relu + truncation pack (feeds sigmoid logit: safe)
        #pragma unroll
        for (int j = 0; j < 4; ++j) {
            unsigned up = pu.w[j], uq = qu.w[j];
            float plo = __uint_as_float(up << 16);
            float phi = __uint_as_float(up & 0xffff0000u);
            float qlo = __uint_as_float(uq << 16);
            float qhi = __uint_as_float(uq & 0xffff0000u);
            float rlo = fmaxf(plo + qlo, 0.f);
            float rhi = fmaxf(phi + qhi, 0.f);
            af.w[j] = (__float_as_uint(rhi) & 0xffff0000u) | (__float_as_uint(rlo) >> 16);
        }
        __syncthreads();
        #pragma unroll
        for (int ct = 0; ct < 8; ++ct) {
            BF8 bfm;
            bfm.v = *(const bf16x8*)&Bs[(ct*16 + lr)*72 + lk*8];
            acc[ct] = __builtin_amdgcn_mfma_f32_16x16x32_bf16(af.v, bfm.v, acc[ct], 0, 0, 0);
        }
    }
    float part[4] = {0.f,0.f,0.f,0.f};
    #pragma unroll
    for (int ct = 0; ct < 8; ++ct) {
        int c = ct*16 + lr;
        float b2v = b2[c], w3v = w3[c];
        #pragma unroll
        for (int g = 0; g < 4; ++g)
            part[g] += fmaxf(acc[ct][g] + b2v, 0.f) * w3v;
    }
    #pragma unroll
    for (int m = 1; m < 16; m <<= 1)
        #pragma unroll
        for (int g = 0; g < 4; ++g)
            part[g] += __shfl_xor(part[g], m, 64);
    if (lr == 0) {
        float b3 = b3p[0];
        #pragma unroll
        for (int g = 0; g < 4; ++g) {
            int rr = row0 + lk*4 + g;
            att[rr] = 1.f/(1.f + expf(-(part[g] + b3)));
        }
    }
}

// ============================ misc ============================
__global__ void k_bias_fill(float* __restrict__ dst, const float* __restrict__ bias, int n){
    int i = blockIdx.x*256 + threadIdx.x;
    if (i < n) dst[i] = bias[i & 127];
}
__global__ void k_f2b(const float* __restrict__ src, ushort* __restrict__ dst, int n){
    int i = blockIdx.x*256 + threadIdx.x;
    if (i < n) dst[i] = f2bf(src[i]);
}

// ============================ hid concat (fp32 + bf16 shadow) ============================
__global__ void k_hid(const float* __restrict__ ts_res, const float* __restrict__ ts_temp,
                      const float* __restrict__ node_emb, const float* __restrict__ tid_emb,
                      const float* __restrict__ diw_emb, const float* __restrict__ hist,
                      float* __restrict__ hid, ushort* __restrict__ hidB)
{
    int idx = blockIdx.x*256 + threadIdx.x;
    if (idx >= RBN*320) return;
    int r = idx / 320, c = idx - r*320;
    int b = r / N_, n = r - b*N_;
    float v;
    if (c < 64)        v = ts_res[(size_t)r*64 + c];
    else if (c < 128)  v = ts_temp[(size_t)r*64 + (c-64)];
    else if (c < 192)  v = node_emb[(size_t)n*64 + (c-128)];
    else if (c < 256) {
        int tid = (int)hist[((size_t)(b*L_ + (L_-1))*N_ + n)*3 + 1];
        v = tid_emb[(size_t)tid*64 + (c-192)];
    } else {
        int diw = (int)hist[((size_t)(b*L_ + (L_-1))*N_ + n)*3 + 2];
        v = diw_emb[(size_t)diw*64 + (c-256)];
    }
    hid[idx] = v;
    hidB[idx] = f2bf(v);
}

// =====================================================================================
extern "C" void kernel_launch(void* const* d_in, const int* in_sizes, int n_in,
                              void* d_out, int out_size, void* d_ws, size_t ws_size,
                              hipStream_t stream)
{
    (void)in_sizes; (void)n_in; (void)out_size; (void)ws_size;
    const float* hist      = (const float*)d_in[0];
    const int*   ei_sp     = (const int*)  d_in[1];
    const int*   ei_tp     = (const int*)  d_in[2];
    const float* node_emb  = (const float*)d_in[3];
    const float* tid_emb   = (const float*)d_in[4];
    const float* diw_emb   = (const float*)d_in[5];
    const float* start_w   = (const float*)d_in[6];
    const float* start_b   = (const float*)d_in[7];
    const float* ts_w      = (const float*)d_in[8];
    const float* ts_b      = (const float*)d_in[9];
    const float* tr_spat_w = (const float*)d_in[10];
    const float* tr_spat_b = (const float*)d_in[11];
    const float* inv_spat_w= (const float*)d_in[12];
    const float* inv_spat_b= (const float*)d_in[13];
    const float* tr_temp_w = (const float*)d_in[14];
    const float* tr_temp_b = (const float*)d_in[15];
    const float* inv_temp_w= (const float*)d_in[16];
    const float* inv_temp_b= (const float*)d_in[17];
    const float* gat_sp_w  = (const float*)d_in[18];
    const float* gat_sp_as = (const float*)d_in[19];
    const float* gat_sp_ad = (const float*)d_in[20];
    const float* gat_sp_b  = (const float*)d_in[21];
    const float* ext_sp_w1 = (const float*)d_in[22];
    const float* ext_sp_b1 = (const float*)d_in[23];
    const float* ext_sp_w2 = (const float*)d_in[24];
    const float* ext_sp_b2 = (const float*)d_in[25];
    const float* ext_sp_w3 = (const float*)d_in[26];
    const float* ext_sp_b3 = (const float*)d_in[27];
    const float* gat_tp_w  = (const float*)d_in[28];
    const float* gat_tp_as = (const float*)d_in[29];
    const float* gat_tp_ad = (const float*)d_in[30];
    const float* gat_tp_b  = (const float*)d_in[31];
    const float* ext_tp_w1 = (const float*)d_in[32];
    const float* ext_tp_b1 = (const float*)d_in[33];
    const float* ext_tp_w2 = (const float*)d_in[34];
    const float* ext_tp_b2 = (const float*)d_in[35];
    const float* ext_tp_w3 = (const float*)d_in[36];
    const float* ext_tp_b3 = (const float*)d_in[37];
    const float* enc_w1    = (const float*)d_in[38];
    const float* enc_b1    = (const float*)d_in[39];
    const float* enc_w2    = (const float*)d_in[40];
    const float* enc_b2    = (const float*)d_in[41];
    const float* reg_w     = (const float*)d_in[42];
    const float* reg_b     = (const float*)d_in[43];
    float* out = (float*)d_out;

    // ---------------- workspace layout (byte-granular, 256B aligned) ----------------
    size_t o = 0;
    char* wsb = (char*)d_ws;
    auto allocB = [&](size_t bytes) -> void* {
        void* p = wsb + o;
        o += (bytes + 255) & ~(size_t)255;
        return p;
    };
    // big reusable arenas
    void* bufA = allocB((size_t)RBN*768*2);   // resHi -> AT[384][56512]bf16 -> hid fp32[RBN][320]
    void* bufB = allocB((size_t)RBN*768*2);   // resLo -> P_sp[RBN][512]bf16 -> temp_back[384][56512]bf16
    void* bufC = allocB((size_t)RBN*512*2);   // Q_sp -> hidB[RBN][320]bf16
    void* bufD = allocB((size_t)RBN*320*2);   // R1b (encoder temp bf16)
    float*  ts_res  = (float*)allocB((size_t)RBN*64*4);
    ushort* spaB    = (ushort*)allocB((size_t)RBN*128*2);  // spa_in -> spa_out
    ushort* hB      = (ushort*)allocB((size_t)RBN*128*2);  // h_sp -> h_tp
    float*  sc_s    = (float*)allocB((size_t)RBN*4*4);
    float*  sc_d    = (float*)allocB((size_t)RBN*4*4);
    unsigned* nmax  = (unsigned*)allocB((size_t)RBN*4*4);
    float*  nsum    = (float*)allocB((size_t)RBN*4*4);
    float*  a_buf   = (float*)allocB((size_t)B_*E_SP*4*4);
    float*  att     = (float*)allocB((size_t)B_*E_SP*4);
    ushort* embB    = (ushort*)allocB((size_t)RBN*128*2);
    int*    csr     = (int*)allocB(17024*4);
    float*  temp_in = (float*)allocB((size_t)RBL*128*4);
    ushort* tempB   = (ushort*)allocB((size_t)RBL*128*2);
    ushort* toutB   = (ushort*)allocB((size_t)RBL*128*2);
    ushort* P_t     = (ushort*)allocB((size_t)RBL*512*2);
    ushort* Q_t     = (ushort*)allocB((size_t)RBL*512*2);
    float*  ts_temp = (float*)allocB((size_t)RBN*64*4);
    // weight preps
    ushort* W2T_sp  = (ushort*)allocB(512*128*2);
    ushort* W2T_tp  = (ushort*)allocB(512*128*2);
    ushort* WtT     = (ushort*)allocB((size_t)128*NDM*2);   // tr_temp_w^T
    ushort* itWT    = (ushort*)allocB((size_t)NDM*128*2);   // inv_temp_w^T
    ushort* tspWT   = (ushort*)allocB(128*768*2);           // tr_spat_w^T
    ushort* ispWT   = (ushort*)allocB(768*128*2);           // inv_spat_w^T
    ushort* gspWT   = (ushort*)allocB(128*128*2);
    ushort* gtpWT   = (ushort*)allocB(128*128*2);
    ushort* w1aT_sp = (ushort*)allocB(512*128*2);
    ushort* w1bT_sp = (ushort*)allocB(512*128*2);
    ushort* w1aT_tp = (ushort*)allocB(512*128*2);
    ushort* w1bT_tp = (ushort*)allocB(512*128*2);
    ushort* w1T_enc = (ushort*)allocB((size_t)3*320*320*2);
    ushort* w2T_enc = (ushort*)allocB((size_t)3*320*320*2);
    ushort* tswT_hi = (ushort*)allocB(64*768*2);
    ushort* tswT_lo = (ushort*)allocB(64*768*2);
    ushort* reg_wT  = (ushort*)allocB(16*320*2);

    ushort* resHi = (ushort*)bufA;
    ushort* resLo = (ushort*)bufB;
    ushort* AT    = (ushort*)bufA;    // [384][56512]
    float*  hid   = (float*)bufA;     // [RBN][320] fp32
    ushort* P_sp  = (ushort*)bufB;    // [RBN][512]
    ushort* tback = (ushort*)bufB;    // [384][56512]
    ushort* Q_sp  = (ushort*)bufC;
    ushort* hidB  = (ushort*)bufC;
    ushort* R1b   = (ushort*)bufD;

    int* counts_sp = csr;
    int* off_sp    = csr + 883;
    int* cur_sp    = csr + 1767;
    int* list_sp   = csr + 2650;
    int* counts_tp = csr + 16778;
    int* off_tp    = csr + 16790;
    int* cur_tp    = csr + 16803;
    int* list_tp   = csr + 16815;

    // ---------------- CSR builds + weight prep ----------------
    hipMemsetAsync(counts_sp, 0, 883*4, stream);
    k_count<<<cdiv_h(E_SP,256),256,0,stream>>>(ei_sp, E_SP, counts_sp);
    k_scan<<<1,1024,0,stream>>>(counts_sp, off_sp, cur_sp, 883);
    k_fill<<<cdiv_h(E_SP,256),256,0,stream>>>(ei_sp, E_SP, cur_sp, list_sp);
    hipMemsetAsync(counts_tp, 0, 12*4, stream);
    k_count<<<1,256,0,stream>>>(ei_tp, E_TP, counts_tp);
    k_scan<<<1,1024,0,stream>>>(counts_tp, off_tp, cur_tp, 12);
    k_fill<<<1,256,0,stream>>>(ei_tp, E_TP, cur_tp, list_tp);
    k_prepW2<<<cdiv_h(512*128,256),256,0,stream>>>(ext_sp_w2, W2T_sp);
    k_prepW2<<<cdiv_h(512*128,256),256,0,stream>>>(ext_tp_w2, W2T_tp);
    k_prepWtT<<<cdiv_h(NDM,128),256,0,stream>>>(tr_temp_w, WtT);
    k_prepT_big<<<NDM/64,256,0,stream>>>(inv_temp_w, itWT);
    k_prepT<<<cdiv_h(768*128,256),256,0,stream>>>(tr_spat_w, tspWT, 768, 128);
    k_prepT<<<cdiv_h(128*768,256),256,0,stream>>>(inv_spat_w, ispWT, 128, 768);
    k_prepT<<<cdiv_h(128*128,256),256,0,stream>>>(gat_sp_w, gspWT, 128, 128);
    k_prepT<<<cdiv_h(128*128,256),256,0,stream>>>(gat_tp_w, gtpWT, 128, 128);
    k_prepT<<<cdiv_h(128*512,256),256,0,stream>>>(ext_sp_w1,           w1aT_sp, 128, 512);
    k_prepT<<<cdiv_h(128*512,256),256,0,stream>>>(ext_sp_w1 + 128*512, w1bT_sp, 128, 512);
    k_prepT<<<cdiv_h(128*512,256),256,0,stream>>>(ext_tp_w1,           w1aT_tp, 128, 512);
    k_prepT<<<cdiv_h(128*512,256),256,0,stream>>>(ext_tp_w1 + 128*512, w1bT_tp, 128, 512);
    for (int i = 0; i < 3; ++i) {
        k_prepT<<<cdiv_h(320*320,256),256,0,stream>>>(enc_w1 + (size_t)i*320*320, w1T_enc + (size_t)i*320*320, 320, 320);
        k_prepT<<<cdiv_h(320*320,256),256,0,stream>>>(enc_w2 + (size_t)i*320*320, w2T_enc + (size_t)i*320*320, 320, 320);
    }
    k_prepT_hl<<<cdiv_h(768*64,256),256,0,stream>>>(ts_w, tswT_hi, tswT_lo, 768, 64);
    hipMemsetAsync(reg_wT, 0, 16*320*2, stream);
    k_prepT<<<cdiv_h(320*12,256),256,0,stream>>>(reg_w, reg_wT, 320, 12);

    // ---------------- res (hi/lo) / ts_res (hi-lo MFMA) / spa_in ----------------
    k_res<<<cdiv_h(RBN*LDM,256),256,0,stream>>>(hist, start_w, start_b, resHi, resLo);
    mgemm_hl<4><<<dim3(1,442),256,0,stream>>>(resHi, resLo, tswT_hi, tswT_lo, ts_b, ts_res,
                                              RBN, 64, LDM);
    mgemm<8,0,0,false,false><<<dim3(1,442),256,0,stream>>>(resHi, tspWT, tr_spat_b, nullptr,
                                                           spaB, RBN, 128, LDM);

    // ---------------- spatial GAT ----------------
    mgemm<8,0,0,false,false><<<dim3(1,442),256,0,stream>>>(spaB, gspWT, nullptr, nullptr,
                                                           hB, RBN, 128, 128);
    k_sc<<<cdiv_h(RBN,256),256,0,stream>>>(hB, gat_sp_as, gat_sp_ad, sc_s, sc_d, RBN);
    hipMemsetAsync(nmax, 0, (size_t)RBN*4*4, stream);
    hipMemsetAsync(nsum, 0, (size_t)RBN*4*4, stream);
    k_att1<<<cdiv_h(B_*E_SP,256),256,0,stream>>>(sc_s, sc_d, ei_sp, E_SP, N_, a_buf, nmax);
    k_att2<<<cdiv_h(B_*E_SP,256),256,0,stream>>>(ei_sp, E_SP, N_, a_buf, nmax, nsum);
    k_gather<false><<<RBN,128,0,stream>>>(hB, a_buf, nsum, nullptr, ei_sp, off_sp, list_sp,
                                          gat_sp_b, embB, E_SP, N_);
    mgemm<8,0,0,false,false><<<dim3(4,442),256,0,stream>>>(embB, w1aT_sp, ext_sp_b1, nullptr,
                                                           P_sp, RBN, 512, 128);
    mgemm<8,0,0,false,false><<<dim3(4,442),256,0,stream>>>(embB, w1bT_sp, nullptr, nullptr,
                                                           Q_sp, RBN, 512, 128);
    ext2_mfma<<<(B_*E_SP)/64,256,0,stream>>>(P_sp, Q_sp, W2T_sp, ext_sp_b2, ext_sp_w3,
                                             ext_sp_b3, ei_sp, att, E_SP, N_);
    k_gather<true><<<RBN,128,0,stream>>>(hB, a_buf, nsum, att, ei_sp, off_sp, list_sp,
                                         gat_sp_b, spaB, E_SP, N_);

    // ---------------- back-projection (bf16 AT) + temporal input (MFMA split-K) ----------
    mgemm<8,0,3,false,false><<<dim3(6,442),256,0,stream>>>(spaB, ispWT, inv_spat_b, nullptr,
                                                           AT, RBN, 768, 128);
    k_bias_fill<<<cdiv_h(RBL*128,256),256,0,stream>>>(temp_in, tr_temp_b, RBL*128);
    temp_in_mfma<<<dim3(56,4),256,0,stream>>>(AT, WtT, temp_in);
    k_f2b<<<cdiv_h(RBL*128,256),256,0,stream>>>(temp_in, tempB, RBL*128);

    // ---------------- temporal GAT ----------------
    mgemm<8,0,0,false,false><<<dim3(1,6),256,0,stream>>>(tempB, gtpWT, nullptr, nullptr,
                                                         hB, RBL, 128, 128);
    k_sc<<<cdiv_h(RBL,256),256,0,stream>>>(hB, gat_tp_as, gat_tp_ad, sc_s, sc_d, RBL);
    hipMemsetAsync(nmax, 0, (size_t)RBL*4*4, stream);
    hipMemsetAsync(nsum, 0, (size_t)RBL*4*4, stream);
    k_att1<<<cdiv_h(B_*E_TP,256),256,0,stream>>>(sc_s, sc_d, ei_tp, E_TP, NT_, a_buf, nmax);
    k_att2<<<cdiv_h(B_*E_TP,256),256,0,stream>>>(ei_tp, E_TP, NT_, a_buf, nmax, nsum);
    k_gather<false><<<RBL,128,0,stream>>>(hB, a_buf, nsum, nullptr, ei_tp, off_tp, list_tp,
                                          gat_tp_b, embB, E_TP, NT_);
    mgemm<8,0,0,false,false><<<dim3(4,6),256,0,stream>>>(embB, w1aT_tp, ext_tp_b1, nullptr,
                                                         P_t, RBL, 512, 128);
    mgemm<8,0,0,false,false><<<dim3(4,6),256,0,stream>>>(embB, w1bT_tp, nullptr, nullptr,
                                                         Q_t, RBL, 512, 128);
    ext2_mfma<<<(B_*E_TP)/64,256,0,stream>>>(P_t, Q_t, W2T_tp, ext_tp_b2, ext_tp_w3,
                                             ext_tp_b3, ei_tp, att, E_TP, NT_);
    k_gather<true><<<RBL,128,0,stream>>>(hB, a_buf, nsum, att, ei_tp, off_tp, list_tp,
                                         gat_tp_b, toutB, E_TP, NT_);

    // ---------------- temporal back-projection + ts_temp ----------------
    mgemm<4,0,0,false,false><<<dim3(883,6),256,0,stream>>>(toutB, itWT, inv_temp_b, nullptr,
                                                           tback, RBL, NDM, 128);
    mgemm<4,1,1,false,false><<<dim3(1,442),256,0,stream>>>(tback, tswT_hi, ts_b, nullptr,
                                                           ts_temp, RBN, 64, LDM);

    // ---------------- concat + residual MLP encoder (MFMA) + regression head ----------------
    k_hid<<<cdiv_h(RBN*320,256),256,0,stream>>>(ts_res, ts_temp, node_emb, tid_emb, diw_emb, hist,
                                                hid, hidB);
    for (int i = 0; i < 3; ++i) {
        mgemm<10,0,0,true,false><<<dim3(2,442),256,0,stream>>>(hidB, w1T_enc + (size_t)i*320*320,
                                                               enc_b1 + i*320, nullptr, R1b, RBN, 320, 320);
        mgemm<10,0,0,false,true><<<dim3(2,442),256,0,stream>>>(R1b, w2T_enc + (size_t)i*320*320,
                                                               enc_b2 + i*320, hid, hidB, RBN, 320, 320);
    }
    mgemm<1,0,2,false,false><<<dim3(1,442),256,0,stream>>>(hidB, reg_wT, reg_b, nullptr,
                                                           out, RBN, 16, 320);
}